// Round 24
// baseline (552.343 us; speedup 1.0000x reference)
//
#include <hip/hip_runtime.h>
#include <math.h>

#define N_NODES 20000
#define N_EDGES 256000
#define ETOT (N_EDGES + N_NODES)
#define NPAD 20096    // 314*64
#define NPAD2 40064   // 626*64
#define NBLK_SCAN ((N_NODES + 255) / 256)   // 79

typedef __attribute__((ext_vector_type(8))) short bf16x8;
typedef __attribute__((ext_vector_type(4))) float f32x4;

__device__ __forceinline__ unsigned short f2bf(float f) {
    unsigned int u = __builtin_bit_cast(unsigned int, f);
    u = (u + 0x7fff + ((u >> 16) & 1)) >> 16;
    return (unsigned short)u;
}

__device__ __forceinline__ float bf2f(unsigned short u) {
    return __builtin_bit_cast(float, (unsigned int)u << 16);
}

__device__ __forceinline__ void gload_lds16(const void* g, void* l) {
    __builtin_amdgcn_global_load_lds(
        (const __attribute__((address_space(1))) void*)g,
        (__attribute__((address_space(3))) void*)l, 16, 0, 0);
}

// unpack uint4 (8 bf16) and fma into acc[8]
__device__ __forceinline__ void fma8(float* acc, uint4 v, float w) {
    acc[0] = fmaf(w, __builtin_bit_cast(float, v.x << 16), acc[0]);
    acc[1] = fmaf(w, __builtin_bit_cast(float, v.x & 0xffff0000u), acc[1]);
    acc[2] = fmaf(w, __builtin_bit_cast(float, v.y << 16), acc[2]);
    acc[3] = fmaf(w, __builtin_bit_cast(float, v.y & 0xffff0000u), acc[3]);
    acc[4] = fmaf(w, __builtin_bit_cast(float, v.z << 16), acc[4]);
    acc[5] = fmaf(w, __builtin_bit_cast(float, v.z & 0xffff0000u), acc[5]);
    acc[6] = fmaf(w, __builtin_bit_cast(float, v.w << 16), acc[6]);
    acc[7] = fmaf(w, __builtin_bit_cast(float, v.w & 0xffff0000u), acc[7]);
}

// ---------------------------------------------------------------------------
// Edge preprocessing: counting sort by dst, deterministic order within segment
// ---------------------------------------------------------------------------

__global__ void hist_kernel(const int* __restrict__ ei, int* __restrict__ cnt) {
    for (int e = blockIdx.x * blockDim.x + threadIdx.x; e < ETOT;
         e += gridDim.x * blockDim.x) {
        int d = (e < N_EDGES) ? ei[N_EDGES + e] : (e - N_EDGES);
        atomicAdd(&cnt[d], 1);
    }
}

__global__ __launch_bounds__(256) void scanA(const int* __restrict__ cnt,
                                             int* __restrict__ incl,
                                             int* __restrict__ bsum) {
    __shared__ int sh[256];
    int t = threadIdx.x;
    int i = blockIdx.x * 256 + t;
    int v = (i < N_NODES) ? cnt[i] : 0;
    sh[t] = v;
    __syncthreads();
#pragma unroll
    for (int off = 1; off < 256; off <<= 1) {
        int u = (t >= off) ? sh[t - off] : 0;
        __syncthreads();
        sh[t] += u;
        __syncthreads();
    }
    if (i < N_NODES) incl[i] = sh[t];
    if (t == 255) bsum[blockIdx.x] = sh[255];
}

__global__ __launch_bounds__(128) void scanB(int* __restrict__ bsum,
                                             int* __restrict__ row_start) {
    __shared__ int sh[128];
    int t = threadIdx.x;
    int v = (t < NBLK_SCAN) ? bsum[t] : 0;
    sh[t] = v;
    __syncthreads();
#pragma unroll
    for (int off = 1; off < 128; off <<= 1) {
        int u = (t >= off) ? sh[t - off] : 0;
        __syncthreads();
        sh[t] += u;
        __syncthreads();
    }
    if (t < NBLK_SCAN) bsum[t] = sh[t] - v;  // exclusive
    if (t == 0) row_start[0] = 0;
}

__global__ __launch_bounds__(256) void scanC(int* __restrict__ cursor,
                                             int* __restrict__ row_start,
                                             const int* __restrict__ bsum) {
    int i = blockIdx.x * 256 + threadIdx.x;
    if (i < N_NODES) {
        int incl = row_start[i + 1] + bsum[blockIdx.x];
        row_start[i + 1] = incl;
        cursor[i] = incl - cursor[i];
    }
}

__global__ void scatter_kernel(const int* __restrict__ ei, int* __restrict__ cursor,
                               int* __restrict__ sorted_id) {
    for (int e = blockIdx.x * blockDim.x + threadIdx.x; e < ETOT;
         e += gridDim.x * blockDim.x) {
        int d = (e < N_EDGES) ? ei[N_EDGES + e] : (e - N_EDGES);
        int pos = atomicAdd(&cursor[d], 1);
        sorted_id[pos] = e;
    }
}

// Deterministic order via wave-parallel rank sort: one wave per node.
__global__ __launch_bounds__(256) void segsort_kernel(
    const int* __restrict__ ei, const int* __restrict__ row_start,
    int* __restrict__ sorted_id, int* __restrict__ sorted_src) {
    int wv = threadIdx.x >> 6, lane = threadIdx.x & 63;
    int n = blockIdx.x * 4 + wv;
    if (n >= N_NODES) return;
    int base = row_start[n];
    int deg = row_start[n + 1] - base;
    if (deg <= 64) {
        int id = (lane < deg) ? sorted_id[base + lane] : 0x7fffffff;
        int rank = 0;
        for (int j = 0; j < deg; j++) {
            int idj = __shfl(id, j);
            rank += (idj < id);
        }
        if (lane < deg) {
            int src = (id < N_EDGES) ? ei[id] : (id - N_EDGES);
            sorted_src[base + rank] = src;
        }
    } else if (lane == 0) {
        for (int i = base + 1; i < base + deg; i++) {
            int v = sorted_id[i];
            int j = i - 1;
            while (j >= base && sorted_id[j] > v) {
                sorted_id[j + 1] = sorted_id[j];
                j--;
            }
            sorted_id[j + 1] = v;
        }
        for (int i = base; i < base + deg; i++) {
            int id = sorted_id[i];
            sorted_src[i] = (id < N_EDGES) ? ei[id] : (id - N_EDGES);
        }
    }
}

// ---------------------------------------------------------------------------
// One-launch setup: cursor zeroing + pad-row zeroing + bf16 conversions
// ---------------------------------------------------------------------------
struct SetupArgs {
    const float* s[7];
    unsigned short* d[7];
    int cum[8];
    int* cursor;
    unsigned short* x16;
    unsigned short* h16n;
    unsigned short* h16wA;
    unsigned short* h16wB;
    unsigned short* st16;
    unsigned short* om16;
};

__global__ __launch_bounds__(256) void setup_all(SetupArgs a) {
    int i = blockIdx.x * 256 + threadIdx.x;
    const int PR = NPAD - N_NODES;  // 96 pad rows
    if (i < N_NODES) a.cursor[i] = 0;
    if (i < PR * 128) {
        a.x16[(size_t)N_NODES * 128 + i] = 0;
        a.h16n[(size_t)N_NODES * 128 + i] = 0;
        a.om16[(size_t)N_NODES * 128 + i] = 0;
    }
    if (i < PR * 512) {
        a.h16wA[(size_t)N_NODES * 512 + i] = 0;
        a.h16wB[(size_t)N_NODES * 512 + i] = 0;
    }
    if (i < (NPAD2 - 2 * N_NODES) * 128) a.st16[(size_t)(2 * N_NODES) * 128 + i] = 0;
    if (i < a.cum[7]) {
        int r = 0;
        while (i >= a.cum[r + 1]) r++;
        int off = i - a.cum[r];
        a.d[r][off] = f2bf(a.s[r][off]);
    }
}

// ---------------------------------------------------------------------------
// bf16 MFMA GEMM, 64x128 tile (BK=64, 4 waves each 32x64).
// Optional fused GAT attention-coefficient epilogue (head = blockIdx.y).
// ---------------------------------------------------------------------------
__global__ __launch_bounds__(256) void gemm_mfma(
    const unsigned short* __restrict__ A, const unsigned short* __restrict__ B,
    const float* __restrict__ bias, float* __restrict__ Cf,
    unsigned short* __restrict__ C16, int R, int K, int ldc,
    const float* __restrict__ a_s, const float* __restrict__ a_d,
    float* __restrict__ al_s, float* __restrict__ al_d, int H) {
    __shared__ unsigned short Al[64 * 64];
    __shared__ unsigned short Bl[128 * 64];
    __shared__ float red_s[4][32], red_d[4][32];
    int tid = threadIdx.x;
    int lane = tid & 63, wv = tid >> 6;
    int wr = (wv >> 1) * 32, wc = (wv & 1) * 64;
    size_t br = (size_t)blockIdx.x * 64;
    size_t bc = (size_t)blockIdx.y * 128;
    f32x4 acc[2][4] = {};
    for (int k0 = 0; k0 < K; k0 += 64) {
#pragma unroll
        for (int i = 0; i < 2; i++) {
            int idx = i * 256 + tid;
            int row = idx >> 3;
            int kb = (idx & 7) << 4;
            gload_lds16((const char*)(A + (br + row) * K + k0) + kb,
                        (char*)Al + idx * 16);
        }
#pragma unroll
        for (int i = 0; i < 4; i++) {
            int idx = i * 256 + tid;
            int row = idx >> 3;
            int kb = (idx & 7) << 4;
            gload_lds16((const char*)(B + (bc + row) * K + k0) + kb,
                        (char*)Bl + idx * 16);
        }
        __syncthreads();
#pragma unroll
        for (int kk = 0; kk < 2; kk++) {
            bf16x8 af[2], bfr[4];
#pragma unroll
            for (int m = 0; m < 2; m++)
                af[m] = *(const bf16x8*)&Al[(wr + m * 16 + (lane & 15)) * 64 +
                                            kk * 32 + (lane >> 4) * 8];
#pragma unroll
            for (int n = 0; n < 4; n++)
                bfr[n] = *(const bf16x8*)&Bl[(wc + n * 16 + (lane & 15)) * 64 +
                                             kk * 32 + (lane >> 4) * 8];
#pragma unroll
            for (int m = 0; m < 2; m++)
#pragma unroll
                for (int n = 0; n < 4; n++)
                    acc[m][n] = __builtin_amdgcn_mfma_f32_16x16x32_bf16(
                        af[m], bfr[n], acc[m][n], 0, 0, 0);
        }
        __syncthreads();
    }

    if (al_s) {
        float asr[4], adr[4];
#pragma unroll
        for (int n = 0; n < 4; n++) {
            int c = (int)bc + wc + n * 16 + (lane & 15);
            asr[n] = a_s[c];
            adr[n] = a_d[c];
        }
        float ps[2][4], pd[2][4];
#pragma unroll
        for (int m = 0; m < 2; m++)
#pragma unroll
            for (int j = 0; j < 4; j++) {
                float s = 0.f, d = 0.f;
#pragma unroll
                for (int n = 0; n < 4; n++) {
                    float v = acc[m][n][j];
                    s = fmaf(v, asr[n], s);
                    d = fmaf(v, adr[n], d);
                }
#pragma unroll
                for (int off = 8; off; off >>= 1) {
                    s += __shfl_xor(s, off);
                    d += __shfl_xor(d, off);
                }
                ps[m][j] = s;
                pd[m][j] = d;
            }
        if ((lane & 15) == 0) {
#pragma unroll
            for (int m = 0; m < 2; m++)
#pragma unroll
                for (int j = 0; j < 4; j++) {
                    int lr = m * 16 + (lane >> 4) * 4 + j;  // 0..31
                    red_s[wv][lr] = ps[m][j];
                    red_d[wv][lr] = pd[m][j];
                }
        }
        __syncthreads();
        if (tid < 64) {
            int half = tid >> 5, lr = tid & 31;
            float s = red_s[half * 2][lr] + red_s[half * 2 + 1][lr];
            float d = red_d[half * 2][lr] + red_d[half * 2 + 1][lr];
            size_t r = br + half * 32 + lr;
            if (r < (size_t)R) {
                al_s[r * H + blockIdx.y] = s;
                al_d[r * H + blockIdx.y] = d;
            }
        }
    }

#pragma unroll
    for (int m = 0; m < 2; m++) {
        int r0 = wr + m * 16 + (lane >> 4) * 4;
#pragma unroll
        for (int n = 0; n < 4; n++) {
            int c = (int)bc + wc + n * 16 + (lane & 15);
            float bv = bias ? bias[c] : 0.f;
#pragma unroll
            for (int j = 0; j < 4; j++) {
                size_t r = br + r0 + j;
                if (r < (size_t)R) {
                    float v = acc[m][n][j] + bv;
                    if (Cf) Cf[r * ldc + c] = v;
                    if (C16) C16[r * ldc + c] = f2bf(v);
                }
            }
        }
    }
}

// ---------------------------------------------------------------------------
// Wave-per-2-nodes GAT aggregation for C=512 (4 heads).
// Each wave owns nodes n0, n0+1; joint interleaved gather doubles the number
// of outstanding row loads per wave.  Per-node fma order unchanged.
// ---------------------------------------------------------------------------
template <int RES>
__global__ __launch_bounds__(256) void gat_agg512(
    const unsigned short* __restrict__ xp16, const float* __restrict__ al_s,
    const float* __restrict__ al_d, const int* __restrict__ row_start,
    const int* __restrict__ srcs, const float* __restrict__ bias,
    const float* __restrict__ gamma, const float* __restrict__ beta,
    const unsigned short* __restrict__ h_res16, unsigned short* __restrict__ out16) {
    const int C = 512;
    int tid = threadIdx.x;
    int lane = tid & 63, wv = tid >> 6;
    int n0 = blockIdx.x * 8 + 2 * wv;
    __shared__ int offw[4][128];      // [wave][node*64 + e]
    __shared__ float logw[4][512];    // [wave][node*256 + e*4 + h]
    if (n0 >= N_NODES) return;
    bool two = (n0 + 1 < N_NODES);
    int head = lane >> 4;
    int e_ = lane >> 2, h_ = lane & 3;

    int baseA[2], degA[2];
    baseA[0] = row_start[n0];
    degA[0] = row_start[n0 + 1] - baseA[0];
    baseA[1] = 0; degA[1] = 0;
    if (two) {
        baseA[1] = row_start[n0 + 1];
        degA[1] = row_start[n0 + 2] - baseA[1];
    }

    float acc[2][8] = {};
    float scaleA[2] = {1.f, 1.f};
    bool fastA[2];
    fastA[0] = (degA[0] <= 64);
    fastA[1] = (degA[1] <= 64);

    // ---- softmax phase per node (fast path fills LDS slot) ----
    for (int nn = 0; nn < 2; nn++) {
        if (nn == 1 && !two) break;
        int n = n0 + nn, base = baseA[nn], deg = degA[nn];
        if (fastA[nn]) {
            float m = -3.4e38f;
            for (int e0 = 0; e0 < deg; e0 += 16) {
                int e = e0 + e_;
                float v = -3.4e38f;
                if (e < deg) {
                    int src = srcs[base + e];
                    if (h_ == 0) offw[wv][nn * 64 + e] = src * (C * 2);
                    float t = al_s[src * 4 + h_] + al_d[n * 4 + h_];
                    v = t > 0.f ? t : 0.2f * t;
                    logw[wv][nn * 256 + e * 4 + h_] = v;
                }
                m = fmaxf(m, v);
            }
#pragma unroll
            for (int off = 4; off <= 32; off <<= 1)
                m = fmaxf(m, __shfl_xor(m, off));
            float s = 0.f;
            for (int e0 = 0; e0 < deg; e0 += 16) {
                int e = e0 + e_;
                if (e < deg) {
                    float p = __expf(logw[wv][nn * 256 + e * 4 + h_] - m);
                    logw[wv][nn * 256 + e * 4 + h_] = p;
                    s += p;
                }
            }
#pragma unroll
            for (int off = 4; off <= 32; off <<= 1) s += __shfl_xor(s, off);
            float inv = 1.0f / (s + 1e-16f);
            scaleA[nn] = __shfl(inv, head);
        }
    }

    // ---- gather ----
    const char* xb = (const char*)xp16 + lane * 16;
    if (fastA[0] && fastA[1] && two) {
        int dmax = max(degA[0], degA[1]);
#pragma unroll 2
        for (int j = 0; j < dmax; j++) {
            if (j < degA[0]) {
                float w = logw[wv][j * 4 + head];
                uint4 vv = *(const uint4*)(xb + offw[wv][j]);
                fma8(acc[0], vv, w);
            }
            if (j < degA[1]) {
                float w = logw[wv][256 + j * 4 + head];
                uint4 vv = *(const uint4*)(xb + offw[wv][64 + j]);
                fma8(acc[1], vv, w);
            }
        }
    } else {
        for (int nn = 0; nn < 2; nn++) {
            if (nn == 1 && !two) break;
            int n = n0 + nn, base = baseA[nn], deg = degA[nn];
            if (fastA[nn]) {
#pragma unroll 4
                for (int j = 0; j < deg; j++) {
                    float w = logw[wv][nn * 256 + j * 4 + head];
                    uint4 vv = *(const uint4*)(xb + offw[wv][nn * 64 + j]);
                    fma8(acc[nn], vv, w);
                }
            } else {
                // streaming generic path (rare)
                float m = -3.4e38f;
                for (int e0 = 0; e0 < deg; e0 += 16) {
                    int e = e0 + e_;
                    if (e < deg) {
                        int src = srcs[base + e];
                        float t = al_s[src * 4 + h_] + al_d[n * 4 + h_];
                        t = t > 0.f ? t : 0.2f * t;
                        m = fmaxf(m, t);
                    }
                }
#pragma unroll
                for (int off = 4; off <= 32; off <<= 1)
                    m = fmaxf(m, __shfl_xor(m, off));
                float s = 0.f;
                for (int e0 = 0; e0 < deg; e0 += 16) {
                    int e = e0 + e_;
                    if (e < deg) {
                        int src = srcs[base + e];
                        float t = al_s[src * 4 + h_] + al_d[n * 4 + h_];
                        t = t > 0.f ? t : 0.2f * t;
                        s += __expf(t - m);
                    }
                }
#pragma unroll
                for (int off = 4; off <= 32; off <<= 1) s += __shfl_xor(s, off);
                float mg = __shfl(m, head);
                float sg = __shfl(s, head);
                float invg = 1.0f / (sg + 1e-16f);
                float aldh = al_d[n * 4 + head];
                for (int j = 0; j < deg; j++) {
                    int src = srcs[base + j];
                    float t = al_s[src * 4 + head] + aldh;
                    t = t > 0.f ? t : 0.2f * t;
                    float w = __expf(t - mg) * invg;
                    uint4 vv = *(const uint4*)(xb + (size_t)src * (C * 2));
                    fma8(acc[nn], vv, w);
                }
                scaleA[nn] = 1.0f;
            }
        }
    }

    // ---- epilogue per node: scale, +bias, ELU, LayerNorm, residual ----
    int ch0 = 8 * lane;
    float4 b0 = *(const float4*)&bias[ch0];
    float4 b1 = *(const float4*)&bias[ch0 + 4];
    float4 g0 = *(const float4*)&gamma[ch0];
    float4 g1 = *(const float4*)&gamma[ch0 + 4];
    float4 be0v = *(const float4*)&beta[ch0];
    float4 be1v = *(const float4*)&beta[ch0 + 4];
    float bbia[8] = {b0.x, b0.y, b0.z, b0.w, b1.x, b1.y, b1.z, b1.w};
    float gg[8] = {g0.x, g0.y, g0.z, g0.w, g1.x, g1.y, g1.z, g1.w};
    float bb[8] = {be0v.x, be0v.y, be0v.z, be0v.w, be1v.x, be1v.y, be1v.z, be1v.w};

    for (int nn = 0; nn < 2; nn++) {
        if (nn == 1 && !two) break;
        int n = n0 + nn;
        float se = scaleA[nn];
        float vals[8];
        float s2 = 0.f, q = 0.f;
#pragma unroll
        for (int k = 0; k < 8; k++) {
            float v = acc[nn][k] * se + bbia[k];
            v = v > 0.f ? v : (__expf(v) - 1.0f);
            vals[k] = v;
            s2 += v;
            q += v * v;
        }
#pragma unroll
        for (int off = 1; off <= 32; off <<= 1) {
            s2 += __shfl_xor(s2, off);
            q += __shfl_xor(q, off);
        }
        float mu = s2 / C;
        float var = q / C - mu * mu;
        float rstd = 1.0f / sqrtf(var + 1e-5f);
#pragma unroll
        for (int k = 0; k < 8; k++) vals[k] = (vals[k] - mu) * rstd * gg[k] + bb[k];
        if (RES == 1) {
            ushort4 r0 = *(const ushort4*)&h_res16[(size_t)n * C + ch0];
            ushort4 r1 = *(const ushort4*)&h_res16[(size_t)n * C + ch0 + 4];
            vals[0] += bf2f(r0.x); vals[1] += bf2f(r0.y);
            vals[2] += bf2f(r0.z); vals[3] += bf2f(r0.w);
            vals[4] += bf2f(r1.x); vals[5] += bf2f(r1.y);
            vals[6] += bf2f(r1.z); vals[7] += bf2f(r1.w);
        }
        uint4 pk;
        pk.x = (unsigned)f2bf(vals[0]) | ((unsigned)f2bf(vals[1]) << 16);
        pk.y = (unsigned)f2bf(vals[2]) | ((unsigned)f2bf(vals[3]) << 16);
        pk.z = (unsigned)f2bf(vals[4]) | ((unsigned)f2bf(vals[5]) << 16);
        pk.w = (unsigned)f2bf(vals[6]) | ((unsigned)f2bf(vals[7]) << 16);
        *(uint4*)&out16[(size_t)n * C + ch0] = pk;
    }
}

// ---------------------------------------------------------------------------
// C=128, 1-head aggregation (one wave per node, 16 lanes/row, 4 edge groups)
// ---------------------------------------------------------------------------
__global__ __launch_bounds__(64) void gat_agg128(
    const unsigned short* __restrict__ xp16, const float* __restrict__ al_s,
    const float* __restrict__ al_d, const int* __restrict__ row_start,
    const int* __restrict__ srcs, const float* __restrict__ bias,
    const float* __restrict__ gamma, const float* __restrict__ beta,
    const unsigned short* __restrict__ h_res16, unsigned short* __restrict__ out16,
    unsigned short* __restrict__ out2_16, int out2_stride) {
    const int C = 128;
    int n = blockIdx.x;
    int lane = threadIdx.x & 63;
    __shared__ int off_sh[64];
    __shared__ float w_sh[64];
    __shared__ float m_sh, s_sh;
    int base = row_start[n];
    int deg = row_start[n + 1] - base;

    float acc[8] = {};

    if (deg <= 64) {
        float v = -3.4e38f;
        if (lane < deg) {
            int src = srcs[base + lane];
            off_sh[lane] = src * (C * 2);
            float t = al_s[src] + al_d[n];
            v = t > 0.f ? t : 0.2f * t;
        }
        float m = v;
#pragma unroll
        for (int off = 32; off; off >>= 1) m = fmaxf(m, __shfl_xor(m, off));
        float p = (lane < deg) ? __expf(v - m) : 0.f;
        float s = p;
#pragma unroll
        for (int off = 32; off; off >>= 1) s += __shfl_xor(s, off);
        s += 1e-16f;
        if (lane < deg) w_sh[lane] = p / s;
        __syncthreads();
        int li = lane & 15, rg = lane >> 4;
        const char* xb = (const char*)xp16 + li * 16;
        for (int j = rg; j < deg; j += 4) {
            uint4 vv = *(const uint4*)(xb + off_sh[j]);
            fma8(acc, vv, w_sh[j]);
        }
    } else {
        float ald = al_d[n];
        float m = -3.4e38f;
        for (int e = lane; e < deg; e += 64) {
            float v = al_s[srcs[base + e]] + ald;
            v = v > 0.f ? v : 0.2f * v;
            m = fmaxf(m, v);
        }
#pragma unroll
        for (int off = 32; off; off >>= 1) m = fmaxf(m, __shfl_xor(m, off));
        float s = 0.f;
        for (int e = lane; e < deg; e += 64) {
            float v = al_s[srcs[base + e]] + ald;
            v = v > 0.f ? v : 0.2f * v;
            s += __expf(v - m);
        }
#pragma unroll
        for (int off = 32; off; off >>= 1) s += __shfl_xor(s, off);
        if (lane == 0) { m_sh = m; s_sh = s + 1e-16f; }
        __syncthreads();
        float mh = m_sh, ssh = s_sh;
        int li = lane & 15, rg = lane >> 4;
        const char* xb = (const char*)xp16 + li * 16;
        for (int j = rg; j < deg; j += 4) {
            int src = srcs[base + j];
            float t = al_s[src] + ald;
            t = t > 0.f ? t : 0.2f * t;
            float w = __expf(t - mh) / ssh;
            uint4 vv = *(const uint4*)(xb + (size_t)src * (C * 2));
            fma8(acc, vv, w);
        }
    }

    // combine 4 edge-groups via shfl; 8 ch/lane epilogue
#pragma unroll
    for (int k = 0; k < 8; k++) {
        acc[k] += __shfl_xor(acc[k], 16);
        acc[k] += __shfl_xor(acc[k], 32);
    }
    int li = lane & 15;
    int ch0 = 8 * li;
    float vals[8];
    float4 b0 = *(const float4*)&bias[ch0];
    float4 b1 = *(const float4*)&bias[ch0 + 4];
    vals[0] = acc[0] + b0.x; vals[1] = acc[1] + b0.y;
    vals[2] = acc[2] + b0.z; vals[3] = acc[3] + b0.w;
    vals[4] = acc[4] + b1.x; vals[5] = acc[5] + b1.y;
    vals[6] = acc[6] + b1.z; vals[7] = acc[7] + b1.w;
    float s = 0.f, q = 0.f;
#pragma unroll
    for (int k = 0; k < 8; k++) {
        vals[k] = vals[k] > 0.f ? vals[k] : (__expf(vals[k]) - 1.0f);
        s += vals[k];
        q += vals[k] * vals[k];
    }
#pragma unroll
    for (int off = 8; off; off >>= 1) {
        s += __shfl_xor(s, off);
        q += __shfl_xor(q, off);
    }
    float mu = s / C;
    float var = q / C - mu * mu;
    float rstd = 1.0f / sqrtf(var + 1e-5f);
    float4 g0 = *(const float4*)&gamma[ch0];
    float4 g1 = *(const float4*)&gamma[ch0 + 4];
    float4 be0v = *(const float4*)&beta[ch0];
    float4 be1v = *(const float4*)&beta[ch0 + 4];
    float gg[8] = {g0.x, g0.y, g0.z, g0.w, g1.x, g1.y, g1.z, g1.w};
    float bb[8] = {be0v.x, be0v.y, be0v.z, be0v.w, be1v.x, be1v.y, be1v.z, be1v.w};
#pragma unroll
    for (int k = 0; k < 8; k++) vals[k] = (vals[k] - mu) * rstd * gg[k] + bb[k];
    {
        const unsigned short* r = &h_res16[(size_t)n * 512 + 4 * ch0];
#pragma unroll
        for (int k = 0; k < 8; k++) {
            ushort4 rv = *(const ushort4*)&r[4 * k];
            vals[k] += 0.25f * (bf2f(rv.x) + bf2f(rv.y) + bf2f(rv.z) + bf2f(rv.w));
        }
    }
    if (lane < 16) {
        uint4 pk;
        pk.x = (unsigned)f2bf(vals[0]) | ((unsigned)f2bf(vals[1]) << 16);
        pk.y = (unsigned)f2bf(vals[2]) | ((unsigned)f2bf(vals[3]) << 16);
        pk.z = (unsigned)f2bf(vals[4]) | ((unsigned)f2bf(vals[5]) << 16);
        pk.w = (unsigned)f2bf(vals[6]) | ((unsigned)f2bf(vals[7]) << 16);
        if (out16) *(uint4*)&out16[(size_t)n * C + ch0] = pk;
        if (out2_16) *(uint4*)&out2_16[(size_t)n * out2_stride + ch0] = pk;
    }
}

// ---------------------------------------------------------------------------
// Temporal self-attention over T=2 states. qkv16:[2N,384] bf16 -> om16 bf16
// ---------------------------------------------------------------------------
__global__ __launch_bounds__(128) void temporal_attn(
    const unsigned short* __restrict__ qkv16, unsigned short* __restrict__ om16) {
    __shared__ float sh[768];
    int n = blockIdx.x;
    int c = threadIdx.x;
    for (int i = c; i < 768; i += 128) {
        int t = i / 384;
        sh[i] = bf2f(qkv16[(size_t)(n * 2 + t) * 384 + (i - t * 384)]);
    }
    __syncthreads();
    int head = c >> 5;
    int hb = head * 32;
    const float scale = 0.17677669529663687f;
    float o[2];
#pragma unroll
    for (int qt = 0; qt < 2; qt++) {
        float s0 = 0.f, s1 = 0.f;
#pragma unroll
        for (int d = 0; d < 32; d++) {
            float qv = sh[qt * 384 + hb + d];
            s0 = fmaf(qv, sh[0 * 384 + 128 + hb + d], s0);
            s1 = fmaf(qv, sh[1 * 384 + 128 + hb + d], s1);
        }
        s0 *= scale; s1 *= scale;
        float m = fmaxf(s0, s1);
        float p0 = __expf(s0 - m), p1 = __expf(s1 - m);
        float inv = 1.0f / (p0 + p1);
        o[qt] = p0 * inv * sh[0 * 384 + 256 + c] + p1 * inv * sh[1 * 384 + 256 + c];
    }
    om16[(size_t)n * 128 + c] = f2bf(0.5f * (o[0] + o[1]));
}

// ---------------------------------------------------------------------------

extern "C" void kernel_launch(void* const* d_in, const int* in_sizes, int n_in,
                              void* d_out, int out_size, void* d_ws, size_t ws_size,
                              hipStream_t stream) {
    const float* x   = (const float*)d_in[0];
    const int*   ei  = (const int*)d_in[1];
    const float* Wp  = (const float*)d_in[2];
    const float* bp  = (const float*)d_in[3];
    const float* W0  = (const float*)d_in[4];
    const float* as0 = (const float*)d_in[5];
    const float* ad0 = (const float*)d_in[6];
    const float* b0  = (const float*)d_in[7];
    const float* W1  = (const float*)d_in[8];
    const float* as1 = (const float*)d_in[9];
    const float* ad1 = (const float*)d_in[10];
    const float* b1  = (const float*)d_in[11];
    const float* W2  = (const float*)d_in[12];
    const float* as2 = (const float*)d_in[13];
    const float* ad2 = (const float*)d_in[14];
    const float* b2  = (const float*)d_in[15];
    const float* g0  = (const float*)d_in[16];
    const float* be0 = (const float*)d_in[17];
    const float* g1  = (const float*)d_in[18];
    const float* be1 = (const float*)d_in[19];
    const float* g2  = (const float*)d_in[20];
    const float* be2 = (const float*)d_in[21];
    const float* Wqkv = (const float*)d_in[22];
    const float* bqkv = (const float*)d_in[23];
    const float* Wo  = (const float*)d_in[24];
    const float* bo  = (const float*)d_in[25];
    float* out = (float*)d_out;

    const int N = N_NODES;
    float* f = (float*)d_ws;
    // fp32 buffers (attention coefficients only)
    float* als = f;                     // [N,4]
    float* ald = als + (size_t)N * 4;   // [N,4]
    // int buffers
    int* row_start  = (int*)(ald + (size_t)N * 4);
    int* cursor     = row_start + (N + 1);
    int* sorted_id  = cursor + N;
    int* sorted_src = sorted_id + ETOT;
    int* bsum       = sorted_src + ETOT;          // NBLK_SCAN
    // bf16 buffers (aligned to 64B for uint4 / global_load_lds dwordx4)
    uintptr_t pa = (uintptr_t)(bsum + NBLK_SCAN + 1);
    pa = (pa + 63) & ~(uintptr_t)63;
    unsigned short* x16   = (unsigned short*)pa;
    unsigned short* h16n  = x16 + (size_t)NPAD * 128;         // [NPAD,128]
    unsigned short* h16wA = h16n + (size_t)NPAD * 128;        // [NPAD,512]
    unsigned short* h16wB = h16wA + (size_t)NPAD * 512;       // [NPAD,512]
    unsigned short* xp16  = h16wB + (size_t)NPAD * 512;       // [NPAD,512]
    unsigned short* st16  = xp16 + (size_t)NPAD * 512;        // [NPAD2,128]
    unsigned short* qkv16 = st16 + (size_t)NPAD2 * 128;       // [NPAD2,384]
    unsigned short* om16  = qkv16 + (size_t)NPAD2 * 384;      // [NPAD,128]
    unsigned short* w16   = om16 + (size_t)NPAD * 128;
    unsigned short* Wp16   = w16;
    unsigned short* W016   = Wp16 + 128 * 128;
    unsigned short* W116   = W016 + 512 * 128;
    unsigned short* W216   = W116 + 512 * 512;
    unsigned short* Wqkv16 = W216 + 128 * 512;
    unsigned short* Wo16   = Wqkv16 + 384 * 128;

    // ---- one-launch setup: cursor zero + pad zero + bf16 conversions ----
    {
        SetupArgs a;
        const float* srcs7[7] = {Wp, W0, W1, W2, Wqkv, Wo, x};
        unsigned short* dsts7[7] = {Wp16, W016, W116, W216, Wqkv16, Wo16, x16};
        int sizes7[7] = {128 * 128, 512 * 128, 512 * 512, 128 * 512,
                         384 * 128, 128 * 128, N_NODES * 128};
        int c = 0;
        a.cum[0] = 0;
        for (int i = 0; i < 7; i++) {
            a.s[i] = srcs7[i];
            a.d[i] = dsts7[i];
            c += sizes7[i];
            a.cum[i + 1] = c;
        }
        a.cursor = cursor;
        a.x16 = x16; a.h16n = h16n; a.h16wA = h16wA; a.h16wB = h16wB;
        a.st16 = st16; a.om16 = om16;
        setup_all<<<(c + 255) / 256, 256, 0, stream>>>(a);
    }

    // ---- edge preprocessing (deterministic counting sort by dst) ----
    hist_kernel<<<1024, 256, 0, stream>>>(ei, cursor);
    scanA<<<NBLK_SCAN, 256, 0, stream>>>(cursor, row_start + 1, bsum);
    scanB<<<1, 128, 0, stream>>>(bsum, row_start);
    scanC<<<NBLK_SCAN, 256, 0, stream>>>(cursor, row_start, bsum);
    scatter_kernel<<<1024, 256, 0, stream>>>(ei, cursor, sorted_id);
    segsort_kernel<<<(N + 3) / 4, 256, 0, stream>>>(ei, row_start, sorted_id,
                                                    sorted_src);

    const int GX = NPAD / 64;   // 314
    const int GX2 = NPAD2 / 64; // 626
    const int GA = (N + 7) / 8; // 2500 blocks, 2 nodes per wave
    // ---- input projection -> h16n ----
    {
        dim3 g(GX, 1);
        gemm_mfma<<<g, 256, 0, stream>>>(x16, Wp16, bp, nullptr, h16n, N, 128, 128,
                                         nullptr, nullptr, nullptr, nullptr, 0);
    }

    for (int t = 0; t < 2; t++) {
        // layer 0: 128 -> 512 (4 heads), no residual
        {
            dim3 g(GX, 4);
            gemm_mfma<<<g, 256, 0, stream>>>(h16n, W016, nullptr, nullptr, xp16,
                                             N, 128, 512, as0, ad0, als, ald, 4);
            gat_agg512<0><<<GA, 256, 0, stream>>>(
                xp16, als, ald, row_start, sorted_src, b0, g0, be0, nullptr, h16wA);
        }
        // layer 1: 512 -> 512 (4 heads), residual = h16wA
        {
            dim3 g(GX, 4);
            gemm_mfma<<<g, 256, 0, stream>>>(h16wA, W116, nullptr, nullptr, xp16,
                                             N, 512, 512, as1, ad1, als, ald, 4);
            gat_agg512<1><<<GA, 256, 0, stream>>>(
                xp16, als, ald, row_start, sorted_src, b1, g1, be1, h16wA, h16wB);
        }
        // layer 2: 512 -> 128 (1 head), pooled residual = h16wB
        {
            dim3 g(GX, 1);
            gemm_mfma<<<g, 256, 0, stream>>>(h16wB, W216, nullptr, nullptr, xp16,
                                             N, 512, 128, as2, ad2, als, ald, 1);
            gat_agg128<<<N, 64, 0, stream>>>(
                xp16, als, ald, row_start, sorted_src, b2, g2, be2, h16wB,
                (t == 0) ? h16n : nullptr, st16 + (size_t)t * 128, 256);
        }
    }

    // ---- temporal attention ----
    {
        dim3 g(GX2, 3);
        gemm_mfma<<<g, 256, 0, stream>>>(st16, Wqkv16, bqkv, nullptr, qkv16,
                                         2 * N, 128, 384, nullptr, nullptr,
                                         nullptr, nullptr, 0);
    }
    temporal_attn<<<N, 128, 0, stream>>>(qkv16, om16);
    {
        dim3 g(GX, 1);
        gemm_mfma<<<g, 256, 0, stream>>>(om16, Wo16, bo, out, nullptr,
                                         N, 128, 128, nullptr, nullptr,
                                         nullptr, nullptr, 0);
    }
}

// Round 25
// 506.589 us; speedup vs baseline: 1.0903x; 1.0903x over previous
//
#include <hip/hip_runtime.h>
#include <math.h>

#define N_NODES 20000
#define N_EDGES 256000
#define ETOT (N_EDGES + N_NODES)
#define NPAD 20096    // 314*64
#define NPAD2 40064   // 626*64
#define NBLK_SCAN ((N_NODES + 255) / 256)   // 79

typedef __attribute__((ext_vector_type(8))) short bf16x8;
typedef __attribute__((ext_vector_type(4))) float f32x4;

__device__ __forceinline__ unsigned short f2bf(float f) {
    unsigned int u = __builtin_bit_cast(unsigned int, f);
    u = (u + 0x7fff + ((u >> 16) & 1)) >> 16;
    return (unsigned short)u;
}

__device__ __forceinline__ float bf2f(unsigned short u) {
    return __builtin_bit_cast(float, (unsigned int)u << 16);
}

__device__ __forceinline__ void gload_lds16(const void* g, void* l) {
    __builtin_amdgcn_global_load_lds(
        (const __attribute__((address_space(1))) void*)g,
        (__attribute__((address_space(3))) void*)l, 16, 0, 0);
}

// unpack uint4 (8 bf16) and fma into acc[8]
__device__ __forceinline__ void fma8(float* acc, uint4 v, float w) {
    acc[0] = fmaf(w, __builtin_bit_cast(float, v.x << 16), acc[0]);
    acc[1] = fmaf(w, __builtin_bit_cast(float, v.x & 0xffff0000u), acc[1]);
    acc[2] = fmaf(w, __builtin_bit_cast(float, v.y << 16), acc[2]);
    acc[3] = fmaf(w, __builtin_bit_cast(float, v.y & 0xffff0000u), acc[3]);
    acc[4] = fmaf(w, __builtin_bit_cast(float, v.z << 16), acc[4]);
    acc[5] = fmaf(w, __builtin_bit_cast(float, v.z & 0xffff0000u), acc[5]);
    acc[6] = fmaf(w, __builtin_bit_cast(float, v.w << 16), acc[6]);
    acc[7] = fmaf(w, __builtin_bit_cast(float, v.w & 0xffff0000u), acc[7]);
}

// ---------------------------------------------------------------------------
// Edge preprocessing: counting sort by dst, deterministic order within segment
// ---------------------------------------------------------------------------

__global__ void hist_kernel(const int* __restrict__ ei, int* __restrict__ cnt) {
    for (int e = blockIdx.x * blockDim.x + threadIdx.x; e < ETOT;
         e += gridDim.x * blockDim.x) {
        int d = (e < N_EDGES) ? ei[N_EDGES + e] : (e - N_EDGES);
        atomicAdd(&cnt[d], 1);
    }
}

__global__ __launch_bounds__(256) void scanA(const int* __restrict__ cnt,
                                             int* __restrict__ incl,
                                             int* __restrict__ bsum) {
    __shared__ int sh[256];
    int t = threadIdx.x;
    int i = blockIdx.x * 256 + t;
    int v = (i < N_NODES) ? cnt[i] : 0;
    sh[t] = v;
    __syncthreads();
#pragma unroll
    for (int off = 1; off < 256; off <<= 1) {
        int u = (t >= off) ? sh[t - off] : 0;
        __syncthreads();
        sh[t] += u;
        __syncthreads();
    }
    if (i < N_NODES) incl[i] = sh[t];
    if (t == 255) bsum[blockIdx.x] = sh[255];
}

__global__ __launch_bounds__(128) void scanB(int* __restrict__ bsum,
                                             int* __restrict__ row_start) {
    __shared__ int sh[128];
    int t = threadIdx.x;
    int v = (t < NBLK_SCAN) ? bsum[t] : 0;
    sh[t] = v;
    __syncthreads();
#pragma unroll
    for (int off = 1; off < 128; off <<= 1) {
        int u = (t >= off) ? sh[t - off] : 0;
        __syncthreads();
        sh[t] += u;
        __syncthreads();
    }
    if (t < NBLK_SCAN) bsum[t] = sh[t] - v;  // exclusive
    if (t == 0) row_start[0] = 0;
}

__global__ __launch_bounds__(256) void scanC(int* __restrict__ cursor,
                                             int* __restrict__ row_start,
                                             const int* __restrict__ bsum) {
    int i = blockIdx.x * 256 + threadIdx.x;
    if (i < N_NODES) {
        int incl = row_start[i + 1] + bsum[blockIdx.x];
        row_start[i + 1] = incl;
        cursor[i] = incl - cursor[i];
    }
}

__global__ void scatter_kernel(const int* __restrict__ ei, int* __restrict__ cursor,
                               int* __restrict__ sorted_id) {
    for (int e = blockIdx.x * blockDim.x + threadIdx.x; e < ETOT;
         e += gridDim.x * blockDim.x) {
        int d = (e < N_EDGES) ? ei[N_EDGES + e] : (e - N_EDGES);
        int pos = atomicAdd(&cursor[d], 1);
        sorted_id[pos] = e;
    }
}

// Deterministic order via wave-parallel rank sort: one wave per node.
__global__ __launch_bounds__(256) void segsort_kernel(
    const int* __restrict__ ei, const int* __restrict__ row_start,
    int* __restrict__ sorted_id, int* __restrict__ sorted_src) {
    int wv = threadIdx.x >> 6, lane = threadIdx.x & 63;
    int n = blockIdx.x * 4 + wv;
    if (n >= N_NODES) return;
    int base = row_start[n];
    int deg = row_start[n + 1] - base;
    if (deg <= 64) {
        int id = (lane < deg) ? sorted_id[base + lane] : 0x7fffffff;
        int rank = 0;
        for (int j = 0; j < deg; j++) {
            int idj = __shfl(id, j);
            rank += (idj < id);
        }
        if (lane < deg) {
            int src = (id < N_EDGES) ? ei[id] : (id - N_EDGES);
            sorted_src[base + rank] = src;
        }
    } else if (lane == 0) {
        for (int i = base + 1; i < base + deg; i++) {
            int v = sorted_id[i];
            int j = i - 1;
            while (j >= base && sorted_id[j] > v) {
                sorted_id[j + 1] = sorted_id[j];
                j--;
            }
            sorted_id[j + 1] = v;
        }
        for (int i = base; i < base + deg; i++) {
            int id = sorted_id[i];
            sorted_src[i] = (id < N_EDGES) ? ei[id] : (id - N_EDGES);
        }
    }
}

// ---------------------------------------------------------------------------
// One-launch setup: cursor zeroing + pad-row zeroing + bf16 conversions
// ---------------------------------------------------------------------------
struct SetupArgs {
    const float* s[7];
    unsigned short* d[7];
    int cum[8];
    int* cursor;
    unsigned short* x16;
    unsigned short* h16n;
    unsigned short* h16wA;
    unsigned short* h16wB;
    unsigned short* st16;
    unsigned short* om16;
};

__global__ __launch_bounds__(256) void setup_all(SetupArgs a) {
    int i = blockIdx.x * 256 + threadIdx.x;
    const int PR = NPAD - N_NODES;  // 96 pad rows
    if (i < N_NODES) a.cursor[i] = 0;
    if (i < PR * 128) {
        a.x16[(size_t)N_NODES * 128 + i] = 0;
        a.h16n[(size_t)N_NODES * 128 + i] = 0;
        a.om16[(size_t)N_NODES * 128 + i] = 0;
    }
    if (i < PR * 512) {
        a.h16wA[(size_t)N_NODES * 512 + i] = 0;
        a.h16wB[(size_t)N_NODES * 512 + i] = 0;
    }
    if (i < (NPAD2 - 2 * N_NODES) * 128) a.st16[(size_t)(2 * N_NODES) * 128 + i] = 0;
    if (i < a.cum[7]) {
        int r = 0;
        while (i >= a.cum[r + 1]) r++;
        int off = i - a.cum[r];
        a.d[r][off] = f2bf(a.s[r][off]);
    }
}

// ---------------------------------------------------------------------------
// bf16 MFMA GEMM, 64x128 tile (BK=64, 4 waves each 32x64).
// Optional fused GAT attention-coefficient epilogue (head = blockIdx.y).
// ---------------------------------------------------------------------------
__global__ __launch_bounds__(256) void gemm_mfma(
    const unsigned short* __restrict__ A, const unsigned short* __restrict__ B,
    const float* __restrict__ bias, float* __restrict__ Cf,
    unsigned short* __restrict__ C16, int R, int K, int ldc,
    const float* __restrict__ a_s, const float* __restrict__ a_d,
    float* __restrict__ al_s, float* __restrict__ al_d, int H) {
    __shared__ unsigned short Al[64 * 64];
    __shared__ unsigned short Bl[128 * 64];
    __shared__ float red_s[4][32], red_d[4][32];
    int tid = threadIdx.x;
    int lane = tid & 63, wv = tid >> 6;
    int wr = (wv >> 1) * 32, wc = (wv & 1) * 64;
    size_t br = (size_t)blockIdx.x * 64;
    size_t bc = (size_t)blockIdx.y * 128;
    f32x4 acc[2][4] = {};
    for (int k0 = 0; k0 < K; k0 += 64) {
#pragma unroll
        for (int i = 0; i < 2; i++) {
            int idx = i * 256 + tid;
            int row = idx >> 3;
            int kb = (idx & 7) << 4;
            gload_lds16((const char*)(A + (br + row) * K + k0) + kb,
                        (char*)Al + idx * 16);
        }
#pragma unroll
        for (int i = 0; i < 4; i++) {
            int idx = i * 256 + tid;
            int row = idx >> 3;
            int kb = (idx & 7) << 4;
            gload_lds16((const char*)(B + (bc + row) * K + k0) + kb,
                        (char*)Bl + idx * 16);
        }
        __syncthreads();
#pragma unroll
        for (int kk = 0; kk < 2; kk++) {
            bf16x8 af[2], bfr[4];
#pragma unroll
            for (int m = 0; m < 2; m++)
                af[m] = *(const bf16x8*)&Al[(wr + m * 16 + (lane & 15)) * 64 +
                                            kk * 32 + (lane >> 4) * 8];
#pragma unroll
            for (int n = 0; n < 4; n++)
                bfr[n] = *(const bf16x8*)&Bl[(wc + n * 16 + (lane & 15)) * 64 +
                                             kk * 32 + (lane >> 4) * 8];
#pragma unroll
            for (int m = 0; m < 2; m++)
#pragma unroll
                for (int n = 0; n < 4; n++)
                    acc[m][n] = __builtin_amdgcn_mfma_f32_16x16x32_bf16(
                        af[m], bfr[n], acc[m][n], 0, 0, 0);
        }
        __syncthreads();
    }

    if (al_s) {
        float asr[4], adr[4];
#pragma unroll
        for (int n = 0; n < 4; n++) {
            int c = (int)bc + wc + n * 16 + (lane & 15);
            asr[n] = a_s[c];
            adr[n] = a_d[c];
        }
        float ps[2][4], pd[2][4];
#pragma unroll
        for (int m = 0; m < 2; m++)
#pragma unroll
            for (int j = 0; j < 4; j++) {
                float s = 0.f, d = 0.f;
#pragma unroll
                for (int n = 0; n < 4; n++) {
                    float v = acc[m][n][j];
                    s = fmaf(v, asr[n], s);
                    d = fmaf(v, adr[n], d);
                }
#pragma unroll
                for (int off = 8; off; off >>= 1) {
                    s += __shfl_xor(s, off);
                    d += __shfl_xor(d, off);
                }
                ps[m][j] = s;
                pd[m][j] = d;
            }
        if ((lane & 15) == 0) {
#pragma unroll
            for (int m = 0; m < 2; m++)
#pragma unroll
                for (int j = 0; j < 4; j++) {
                    int lr = m * 16 + (lane >> 4) * 4 + j;  // 0..31
                    red_s[wv][lr] = ps[m][j];
                    red_d[wv][lr] = pd[m][j];
                }
        }
        __syncthreads();
        if (tid < 64) {
            int half = tid >> 5, lr = tid & 31;
            float s = red_s[half * 2][lr] + red_s[half * 2 + 1][lr];
            float d = red_d[half * 2][lr] + red_d[half * 2 + 1][lr];
            size_t r = br + half * 32 + lr;
            if (r < (size_t)R) {
                al_s[r * H + blockIdx.y] = s;
                al_d[r * H + blockIdx.y] = d;
            }
        }
    }

#pragma unroll
    for (int m = 0; m < 2; m++) {
        int r0 = wr + m * 16 + (lane >> 4) * 4;
#pragma unroll
        for (int n = 0; n < 4; n++) {
            int c = (int)bc + wc + n * 16 + (lane & 15);
            float bv = bias ? bias[c] : 0.f;
#pragma unroll
            for (int j = 0; j < 4; j++) {
                size_t r = br + r0 + j;
                if (r < (size_t)R) {
                    float v = acc[m][n][j] + bv;
                    if (Cf) Cf[r * ldc + c] = v;
                    if (C16) C16[r * ldc + c] = f2bf(v);
                }
            }
        }
    }
}

// ---------------------------------------------------------------------------
// agg512 epilogue helper (statically indexed after inlining)
// ---------------------------------------------------------------------------
template <int RES>
__device__ __forceinline__ void epi512(
    int n, const float* acc, float se, int ch0, const float* bbia,
    const float* gg, const float* bb, const unsigned short* __restrict__ h_res16,
    unsigned short* __restrict__ out16) {
    const int C = 512;
    float vals[8];
    float s2 = 0.f, q = 0.f;
#pragma unroll
    for (int k = 0; k < 8; k++) {
        float v = acc[k] * se + bbia[k];
        v = v > 0.f ? v : (__expf(v) - 1.0f);
        vals[k] = v;
        s2 += v;
        q += v * v;
    }
#pragma unroll
    for (int off = 1; off <= 32; off <<= 1) {
        s2 += __shfl_xor(s2, off);
        q += __shfl_xor(q, off);
    }
    float mu = s2 / C;
    float var = q / C - mu * mu;
    float rstd = 1.0f / sqrtf(var + 1e-5f);
#pragma unroll
    for (int k = 0; k < 8; k++) vals[k] = (vals[k] - mu) * rstd * gg[k] + bb[k];
    if (RES == 1) {
        ushort4 r0 = *(const ushort4*)&h_res16[(size_t)n * C + ch0];
        ushort4 r1 = *(const ushort4*)&h_res16[(size_t)n * C + ch0 + 4];
        vals[0] += bf2f(r0.x); vals[1] += bf2f(r0.y);
        vals[2] += bf2f(r0.z); vals[3] += bf2f(r0.w);
        vals[4] += bf2f(r1.x); vals[5] += bf2f(r1.y);
        vals[6] += bf2f(r1.z); vals[7] += bf2f(r1.w);
    }
    uint4 pk;
    pk.x = (unsigned)f2bf(vals[0]) | ((unsigned)f2bf(vals[1]) << 16);
    pk.y = (unsigned)f2bf(vals[2]) | ((unsigned)f2bf(vals[3]) << 16);
    pk.z = (unsigned)f2bf(vals[4]) | ((unsigned)f2bf(vals[5]) << 16);
    pk.w = (unsigned)f2bf(vals[6]) | ((unsigned)f2bf(vals[7]) << 16);
    *(uint4*)&out16[(size_t)n * C + ch0] = pk;
}

// ---------------------------------------------------------------------------
// Wave-per-2-nodes GAT aggregation for C=512 (4 heads), fully static regs.
// N even -> n0, n0+1 always valid; explicit acc0/acc1, no runtime indexing.
// ---------------------------------------------------------------------------
template <int RES>
__global__ __launch_bounds__(256) void gat_agg512(
    const unsigned short* __restrict__ xp16, const float* __restrict__ al_s,
    const float* __restrict__ al_d, const int* __restrict__ row_start,
    const int* __restrict__ srcs, const float* __restrict__ bias,
    const float* __restrict__ gamma, const float* __restrict__ beta,
    const unsigned short* __restrict__ h_res16, unsigned short* __restrict__ out16) {
    const int C = 512;
    int tid = threadIdx.x;
    int lane = tid & 63, wv = tid >> 6;
    int n0 = blockIdx.x * 8 + 2 * wv;  // always < N (N even, grid = N/8)
    int n1 = n0 + 1;
    __shared__ int offw[4][128];       // [wave][node*64 + e]
    __shared__ float logw[4][512];     // [wave][node*256 + e*4 + h]
    int head = lane >> 4;
    int e_ = lane >> 2, h_ = lane & 3;

    int base0 = row_start[n0];
    int deg0 = row_start[n0 + 1] - base0;
    int base1 = row_start[n1];
    int deg1 = row_start[n1 + 1] - base1;

    float acc0[8] = {}, acc1[8] = {};
    float scale0 = 1.f, scale1 = 1.f;
    bool fast0 = (deg0 <= 64), fast1 = (deg1 <= 64);

    // ---- softmax node0 ----
    if (fast0) {
        float m = -3.4e38f;
        for (int e0 = 0; e0 < deg0; e0 += 16) {
            int e = e0 + e_;
            float v = -3.4e38f;
            if (e < deg0) {
                int src = srcs[base0 + e];
                if (h_ == 0) offw[wv][e] = src * (C * 2);
                float t = al_s[src * 4 + h_] + al_d[n0 * 4 + h_];
                v = t > 0.f ? t : 0.2f * t;
                logw[wv][e * 4 + h_] = v;
            }
            m = fmaxf(m, v);
        }
#pragma unroll
        for (int off = 4; off <= 32; off <<= 1) m = fmaxf(m, __shfl_xor(m, off));
        float s = 0.f;
        for (int e0 = 0; e0 < deg0; e0 += 16) {
            int e = e0 + e_;
            if (e < deg0) {
                float p = __expf(logw[wv][e * 4 + h_] - m);
                logw[wv][e * 4 + h_] = p;
                s += p;
            }
        }
#pragma unroll
        for (int off = 4; off <= 32; off <<= 1) s += __shfl_xor(s, off);
        float inv = 1.0f / (s + 1e-16f);
        scale0 = __shfl(inv, head);
    }
    // ---- softmax node1 ----
    if (fast1) {
        float m = -3.4e38f;
        for (int e0 = 0; e0 < deg1; e0 += 16) {
            int e = e0 + e_;
            float v = -3.4e38f;
            if (e < deg1) {
                int src = srcs[base1 + e];
                if (h_ == 0) offw[wv][64 + e] = src * (C * 2);
                float t = al_s[src * 4 + h_] + al_d[n1 * 4 + h_];
                v = t > 0.f ? t : 0.2f * t;
                logw[wv][256 + e * 4 + h_] = v;
            }
            m = fmaxf(m, v);
        }
#pragma unroll
        for (int off = 4; off <= 32; off <<= 1) m = fmaxf(m, __shfl_xor(m, off));
        float s = 0.f;
        for (int e0 = 0; e0 < deg1; e0 += 16) {
            int e = e0 + e_;
            if (e < deg1) {
                float p = __expf(logw[wv][256 + e * 4 + h_] - m);
                logw[wv][256 + e * 4 + h_] = p;
                s += p;
            }
        }
#pragma unroll
        for (int off = 4; off <= 32; off <<= 1) s += __shfl_xor(s, off);
        float inv = 1.0f / (s + 1e-16f);
        scale1 = __shfl(inv, head);
    }

    // ---- gather ----
    const char* xb = (const char*)xp16 + lane * 16;
    if (fast0 && fast1) {
        int dmax = max(deg0, deg1);
#pragma unroll 2
        for (int j = 0; j < dmax; j++) {
            if (j < deg0) {
                float w = logw[wv][j * 4 + head];
                uint4 vv = *(const uint4*)(xb + offw[wv][j]);
                fma8(acc0, vv, w);
            }
            if (j < deg1) {
                float w = logw[wv][256 + j * 4 + head];
                uint4 vv = *(const uint4*)(xb + offw[wv][64 + j]);
                fma8(acc1, vv, w);
            }
        }
    } else {
        // node0
        if (fast0) {
#pragma unroll 4
            for (int j = 0; j < deg0; j++) {
                float w = logw[wv][j * 4 + head];
                uint4 vv = *(const uint4*)(xb + offw[wv][j]);
                fma8(acc0, vv, w);
            }
        } else {
            float m = -3.4e38f;
            for (int e0 = 0; e0 < deg0; e0 += 16) {
                int e = e0 + e_;
                if (e < deg0) {
                    int src = srcs[base0 + e];
                    float t = al_s[src * 4 + h_] + al_d[n0 * 4 + h_];
                    t = t > 0.f ? t : 0.2f * t;
                    m = fmaxf(m, t);
                }
            }
#pragma unroll
            for (int off = 4; off <= 32; off <<= 1) m = fmaxf(m, __shfl_xor(m, off));
            float s = 0.f;
            for (int e0 = 0; e0 < deg0; e0 += 16) {
                int e = e0 + e_;
                if (e < deg0) {
                    int src = srcs[base0 + e];
                    float t = al_s[src * 4 + h_] + al_d[n0 * 4 + h_];
                    t = t > 0.f ? t : 0.2f * t;
                    s += __expf(t - m);
                }
            }
#pragma unroll
            for (int off = 4; off <= 32; off <<= 1) s += __shfl_xor(s, off);
            float mg = __shfl(m, head);
            float sg = __shfl(s, head);
            float invg = 1.0f / (sg + 1e-16f);
            float aldh = al_d[n0 * 4 + head];
            for (int j = 0; j < deg0; j++) {
                int src = srcs[base0 + j];
                float t = al_s[src * 4 + head] + aldh;
                t = t > 0.f ? t : 0.2f * t;
                float w = __expf(t - mg) * invg;
                uint4 vv = *(const uint4*)(xb + (size_t)src * (C * 2));
                fma8(acc0, vv, w);
            }
            scale0 = 1.0f;
        }
        // node1
        if (fast1) {
#pragma unroll 4
            for (int j = 0; j < deg1; j++) {
                float w = logw[wv][256 + j * 4 + head];
                uint4 vv = *(const uint4*)(xb + offw[wv][64 + j]);
                fma8(acc1, vv, w);
            }
        } else {
            float m = -3.4e38f;
            for (int e0 = 0; e0 < deg1; e0 += 16) {
                int e = e0 + e_;
                if (e < deg1) {
                    int src = srcs[base1 + e];
                    float t = al_s[src * 4 + h_] + al_d[n1 * 4 + h_];
                    t = t > 0.f ? t : 0.2f * t;
                    m = fmaxf(m, t);
                }
            }
#pragma unroll
            for (int off = 4; off <= 32; off <<= 1) m = fmaxf(m, __shfl_xor(m, off));
            float s = 0.f;
            for (int e0 = 0; e0 < deg1; e0 += 16) {
                int e = e0 + e_;
                if (e < deg1) {
                    int src = srcs[base1 + e];
                    float t = al_s[src * 4 + h_] + al_d[n1 * 4 + h_];
                    t = t > 0.f ? t : 0.2f * t;
                    s += __expf(t - m);
                }
            }
#pragma unroll
            for (int off = 4; off <= 32; off <<= 1) s += __shfl_xor(s, off);
            float mg = __shfl(m, head);
            float sg = __shfl(s, head);
            float invg = 1.0f / (sg + 1e-16f);
            float aldh = al_d[n1 * 4 + head];
            for (int j = 0; j < deg1; j++) {
                int src = srcs[base1 + j];
                float t = al_s[src * 4 + head] + aldh;
                t = t > 0.f ? t : 0.2f * t;
                float w = __expf(t - mg) * invg;
                uint4 vv = *(const uint4*)(xb + (size_t)src * (C * 2));
                fma8(acc1, vv, w);
            }
            scale1 = 1.0f;
        }
    }

    // ---- epilogue (constants loaded once) ----
    int ch0 = 8 * lane;
    float4 b0 = *(const float4*)&bias[ch0];
    float4 b1 = *(const float4*)&bias[ch0 + 4];
    float4 g0 = *(const float4*)&gamma[ch0];
    float4 g1 = *(const float4*)&gamma[ch0 + 4];
    float4 be0v = *(const float4*)&beta[ch0];
    float4 be1v = *(const float4*)&beta[ch0 + 4];
    float bbia[8] = {b0.x, b0.y, b0.z, b0.w, b1.x, b1.y, b1.z, b1.w};
    float gg[8] = {g0.x, g0.y, g0.z, g0.w, g1.x, g1.y, g1.z, g1.w};
    float bb[8] = {be0v.x, be0v.y, be0v.z, be0v.w, be1v.x, be1v.y, be1v.z, be1v.w};

    epi512<RES>(n0, acc0, scale0, ch0, bbia, gg, bb, h_res16, out16);
    epi512<RES>(n1, acc1, scale1, ch0, bbia, gg, bb, h_res16, out16);
}

// ---------------------------------------------------------------------------
// C=128, 1-head aggregation (one wave per node, 16 lanes/row, 4 edge groups)
// ---------------------------------------------------------------------------
__global__ __launch_bounds__(64) void gat_agg128(
    const unsigned short* __restrict__ xp16, const float* __restrict__ al_s,
    const float* __restrict__ al_d, const int* __restrict__ row_start,
    const int* __restrict__ srcs, const float* __restrict__ bias,
    const float* __restrict__ gamma, const float* __restrict__ beta,
    const unsigned short* __restrict__ h_res16, unsigned short* __restrict__ out16,
    unsigned short* __restrict__ out2_16, int out2_stride) {
    const int C = 128;
    int n = blockIdx.x;
    int lane = threadIdx.x & 63;
    __shared__ int off_sh[64];
    __shared__ float w_sh[64];
    __shared__ float m_sh, s_sh;
    int base = row_start[n];
    int deg = row_start[n + 1] - base;

    float acc[8] = {};

    if (deg <= 64) {
        float v = -3.4e38f;
        if (lane < deg) {
            int src = srcs[base + lane];
            off_sh[lane] = src * (C * 2);
            float t = al_s[src] + al_d[n];
            v = t > 0.f ? t : 0.2f * t;
        }
        float m = v;
#pragma unroll
        for (int off = 32; off; off >>= 1) m = fmaxf(m, __shfl_xor(m, off));
        float p = (lane < deg) ? __expf(v - m) : 0.f;
        float s = p;
#pragma unroll
        for (int off = 32; off; off >>= 1) s += __shfl_xor(s, off);
        s += 1e-16f;
        if (lane < deg) w_sh[lane] = p / s;
        __syncthreads();
        int li = lane & 15, rg = lane >> 4;
        const char* xb = (const char*)xp16 + li * 16;
        for (int j = rg; j < deg; j += 4) {
            uint4 vv = *(const uint4*)(xb + off_sh[j]);
            fma8(acc, vv, w_sh[j]);
        }
    } else {
        float ald = al_d[n];
        float m = -3.4e38f;
        for (int e = lane; e < deg; e += 64) {
            float v = al_s[srcs[base + e]] + ald;
            v = v > 0.f ? v : 0.2f * v;
            m = fmaxf(m, v);
        }
#pragma unroll
        for (int off = 32; off; off >>= 1) m = fmaxf(m, __shfl_xor(m, off));
        float s = 0.f;
        for (int e = lane; e < deg; e += 64) {
            float v = al_s[srcs[base + e]] + ald;
            v = v > 0.f ? v : 0.2f * v;
            s += __expf(v - m);
        }
#pragma unroll
        for (int off = 32; off; off >>= 1) s += __shfl_xor(s, off);
        if (lane == 0) { m_sh = m; s_sh = s + 1e-16f; }
        __syncthreads();
        float mh = m_sh, ssh = s_sh;
        int li = lane & 15, rg = lane >> 4;
        const char* xb = (const char*)xp16 + li * 16;
        for (int j = rg; j < deg; j += 4) {
            int src = srcs[base + j];
            float t = al_s[src] + ald;
            t = t > 0.f ? t : 0.2f * t;
            float w = __expf(t - mh) / ssh;
            uint4 vv = *(const uint4*)(xb + (size_t)src * (C * 2));
            fma8(acc, vv, w);
        }
    }

    // combine 4 edge-groups via shfl; 8 ch/lane epilogue
#pragma unroll
    for (int k = 0; k < 8; k++) {
        acc[k] += __shfl_xor(acc[k], 16);
        acc[k] += __shfl_xor(acc[k], 32);
    }
    int li = lane & 15;
    int ch0 = 8 * li;
    float vals[8];
    float4 b0 = *(const float4*)&bias[ch0];
    float4 b1 = *(const float4*)&bias[ch0 + 4];
    vals[0] = acc[0] + b0.x; vals[1] = acc[1] + b0.y;
    vals[2] = acc[2] + b0.z; vals[3] = acc[3] + b0.w;
    vals[4] = acc[4] + b1.x; vals[5] = acc[5] + b1.y;
    vals[6] = acc[6] + b1.z; vals[7] = acc[7] + b1.w;
    float s = 0.f, q = 0.f;
#pragma unroll
    for (int k = 0; k < 8; k++) {
        vals[k] = vals[k] > 0.f ? vals[k] : (__expf(vals[k]) - 1.0f);
        s += vals[k];
        q += vals[k] * vals[k];
    }
#pragma unroll
    for (int off = 8; off; off >>= 1) {
        s += __shfl_xor(s, off);
        q += __shfl_xor(q, off);
    }
    float mu = s / C;
    float var = q / C - mu * mu;
    float rstd = 1.0f / sqrtf(var + 1e-5f);
    float4 g0 = *(const float4*)&gamma[ch0];
    float4 g1 = *(const float4*)&gamma[ch0 + 4];
    float4 be0v = *(const float4*)&beta[ch0];
    float4 be1v = *(const float4*)&beta[ch0 + 4];
    float gg[8] = {g0.x, g0.y, g0.z, g0.w, g1.x, g1.y, g1.z, g1.w};
    float bb[8] = {be0v.x, be0v.y, be0v.z, be0v.w, be1v.x, be1v.y, be1v.z, be1v.w};
#pragma unroll
    for (int k = 0; k < 8; k++) vals[k] = (vals[k] - mu) * rstd * gg[k] + bb[k];
    {
        const unsigned short* r = &h_res16[(size_t)n * 512 + 4 * ch0];
#pragma unroll
        for (int k = 0; k < 8; k++) {
            ushort4 rv = *(const ushort4*)&r[4 * k];
            vals[k] += 0.25f * (bf2f(rv.x) + bf2f(rv.y) + bf2f(rv.z) + bf2f(rv.w));
        }
    }
    if (lane < 16) {
        uint4 pk;
        pk.x = (unsigned)f2bf(vals[0]) | ((unsigned)f2bf(vals[1]) << 16);
        pk.y = (unsigned)f2bf(vals[2]) | ((unsigned)f2bf(vals[3]) << 16);
        pk.z = (unsigned)f2bf(vals[4]) | ((unsigned)f2bf(vals[5]) << 16);
        pk.w = (unsigned)f2bf(vals[6]) | ((unsigned)f2bf(vals[7]) << 16);
        if (out16) *(uint4*)&out16[(size_t)n * C + ch0] = pk;
        if (out2_16) *(uint4*)&out2_16[(size_t)n * out2_stride + ch0] = pk;
    }
}

// ---------------------------------------------------------------------------
// Temporal self-attention over T=2 states. qkv16:[2N,384] bf16 -> om16 bf16
// ---------------------------------------------------------------------------
__global__ __launch_bounds__(128) void temporal_attn(
    const unsigned short* __restrict__ qkv16, unsigned short* __restrict__ om16) {
    __shared__ float sh[768];
    int n = blockIdx.x;
    int c = threadIdx.x;
    for (int i = c; i < 768; i += 128) {
        int t = i / 384;
        sh[i] = bf2f(qkv16[(size_t)(n * 2 + t) * 384 + (i - t * 384)]);
    }
    __syncthreads();
    int head = c >> 5;
    int hb = head * 32;
    const float scale = 0.17677669529663687f;
    float o[2];
#pragma unroll
    for (int qt = 0; qt < 2; qt++) {
        float s0 = 0.f, s1 = 0.f;
#pragma unroll
        for (int d = 0; d < 32; d++) {
            float qv = sh[qt * 384 + hb + d];
            s0 = fmaf(qv, sh[0 * 384 + 128 + hb + d], s0);
            s1 = fmaf(qv, sh[1 * 384 + 128 + hb + d], s1);
        }
        s0 *= scale; s1 *= scale;
        float m = fmaxf(s0, s1);
        float p0 = __expf(s0 - m), p1 = __expf(s1 - m);
        float inv = 1.0f / (p0 + p1);
        o[qt] = p0 * inv * sh[0 * 384 + 256 + c] + p1 * inv * sh[1 * 384 + 256 + c];
    }
    om16[(size_t)n * 128 + c] = f2bf(0.5f * (o[0] + o[1]));
}

// ---------------------------------------------------------------------------

extern "C" void kernel_launch(void* const* d_in, const int* in_sizes, int n_in,
                              void* d_out, int out_size, void* d_ws, size_t ws_size,
                              hipStream_t stream) {
    const float* x   = (const float*)d_in[0];
    const int*   ei  = (const int*)d_in[1];
    const float* Wp  = (const float*)d_in[2];
    const float* bp  = (const float*)d_in[3];
    const float* W0  = (const float*)d_in[4];
    const float* as0 = (const float*)d_in[5];
    const float* ad0 = (const float*)d_in[6];
    const float* b0  = (const float*)d_in[7];
    const float* W1  = (const float*)d_in[8];
    const float* as1 = (const float*)d_in[9];
    const float* ad1 = (const float*)d_in[10];
    const float* b1  = (const float*)d_in[11];
    const float* W2  = (const float*)d_in[12];
    const float* as2 = (const float*)d_in[13];
    const float* ad2 = (const float*)d_in[14];
    const float* b2  = (const float*)d_in[15];
    const float* g0  = (const float*)d_in[16];
    const float* be0 = (const float*)d_in[17];
    const float* g1  = (const float*)d_in[18];
    const float* be1 = (const float*)d_in[19];
    const float* g2  = (const float*)d_in[20];
    const float* be2 = (const float*)d_in[21];
    const float* Wqkv = (const float*)d_in[22];
    const float* bqkv = (const float*)d_in[23];
    const float* Wo  = (const float*)d_in[24];
    const float* bo  = (const float*)d_in[25];
    float* out = (float*)d_out;

    const int N = N_NODES;
    float* f = (float*)d_ws;
    // fp32 buffers (attention coefficients only)
    float* als = f;                     // [N,4]
    float* ald = als + (size_t)N * 4;   // [N,4]
    // int buffers
    int* row_start  = (int*)(ald + (size_t)N * 4);
    int* cursor     = row_start + (N + 1);
    int* sorted_id  = cursor + N;
    int* sorted_src = sorted_id + ETOT;
    int* bsum       = sorted_src + ETOT;          // NBLK_SCAN
    // bf16 buffers (aligned to 64B for uint4 / global_load_lds dwordx4)
    uintptr_t pa = (uintptr_t)(bsum + NBLK_SCAN + 1);
    pa = (pa + 63) & ~(uintptr_t)63;
    unsigned short* x16   = (unsigned short*)pa;
    unsigned short* h16n  = x16 + (size_t)NPAD * 128;         // [NPAD,128]
    unsigned short* h16wA = h16n + (size_t)NPAD * 128;        // [NPAD,512]
    unsigned short* h16wB = h16wA + (size_t)NPAD * 512;       // [NPAD,512]
    unsigned short* xp16  = h16wB + (size_t)NPAD * 512;       // [NPAD,512]
    unsigned short* st16  = xp16 + (size_t)NPAD * 512;        // [NPAD2,128]
    unsigned short* qkv16 = st16 + (size_t)NPAD2 * 128;       // [NPAD2,384]
    unsigned short* om16  = qkv16 + (size_t)NPAD2 * 384;      // [NPAD,128]
    unsigned short* w16   = om16 + (size_t)NPAD * 128;
    unsigned short* Wp16   = w16;
    unsigned short* W016   = Wp16 + 128 * 128;
    unsigned short* W116   = W016 + 512 * 128;
    unsigned short* W216   = W116 + 512 * 512;
    unsigned short* Wqkv16 = W216 + 128 * 512;
    unsigned short* Wo16   = Wqkv16 + 384 * 128;

    // ---- one-launch setup: cursor zero + pad zero + bf16 conversions ----
    {
        SetupArgs a;
        const float* srcs7[7] = {Wp, W0, W1, W2, Wqkv, Wo, x};
        unsigned short* dsts7[7] = {Wp16, W016, W116, W216, Wqkv16, Wo16, x16};
        int sizes7[7] = {128 * 128, 512 * 128, 512 * 512, 128 * 512,
                         384 * 128, 128 * 128, N_NODES * 128};
        int c = 0;
        a.cum[0] = 0;
        for (int i = 0; i < 7; i++) {
            a.s[i] = srcs7[i];
            a.d[i] = dsts7[i];
            c += sizes7[i];
            a.cum[i + 1] = c;
        }
        a.cursor = cursor;
        a.x16 = x16; a.h16n = h16n; a.h16wA = h16wA; a.h16wB = h16wB;
        a.st16 = st16; a.om16 = om16;
        setup_all<<<(c + 255) / 256, 256, 0, stream>>>(a);
    }

    // ---- edge preprocessing (deterministic counting sort by dst) ----
    hist_kernel<<<1024, 256, 0, stream>>>(ei, cursor);
    scanA<<<NBLK_SCAN, 256, 0, stream>>>(cursor, row_start + 1, bsum);
    scanB<<<1, 128, 0, stream>>>(bsum, row_start);
    scanC<<<NBLK_SCAN, 256, 0, stream>>>(cursor, row_start, bsum);
    scatter_kernel<<<1024, 256, 0, stream>>>(ei, cursor, sorted_id);
    segsort_kernel<<<(N + 3) / 4, 256, 0, stream>>>(ei, row_start, sorted_id,
                                                    sorted_src);

    const int GX = NPAD / 64;   // 314
    const int GX2 = NPAD2 / 64; // 626
    const int GA = (N + 7) / 8; // 2500 blocks, 2 nodes per wave
    // ---- input projection -> h16n ----
    {
        dim3 g(GX, 1);
        gemm_mfma<<<g, 256, 0, stream>>>(x16, Wp16, bp, nullptr, h16n, N, 128, 128,
                                         nullptr, nullptr, nullptr, nullptr, 0);
    }

    for (int t = 0; t < 2; t++) {
        // layer 0: 128 -> 512 (4 heads), no residual
        {
            dim3 g(GX, 4);
            gemm_mfma<<<g, 256, 0, stream>>>(h16n, W016, nullptr, nullptr, xp16,
                                             N, 128, 512, as0, ad0, als, ald, 4);
            gat_agg512<0><<<GA, 256, 0, stream>>>(
                xp16, als, ald, row_start, sorted_src, b0, g0, be0, nullptr, h16wA);
        }
        // layer 1: 512 -> 512 (4 heads), residual = h16wA
        {
            dim3 g(GX, 4);
            gemm_mfma<<<g, 256, 0, stream>>>(h16wA, W116, nullptr, nullptr, xp16,
                                             N, 512, 512, as1, ad1, als, ald, 4);
            gat_agg512<1><<<GA, 256, 0, stream>>>(
                xp16, als, ald, row_start, sorted_src, b1, g1, be1, h16wA, h16wB);
        }
        // layer 2: 512 -> 128 (1 head), pooled residual = h16wB
        {
            dim3 g(GX, 1);
            gemm_mfma<<<g, 256, 0, stream>>>(h16wB, W216, nullptr, nullptr, xp16,
                                             N, 512, 128, as2, ad2, als, ald, 1);
            gat_agg128<<<N, 64, 0, stream>>>(
                xp16, als, ald, row_start, sorted_src, b2, g2, be2, h16wB,
                (t == 0) ? h16n : nullptr, st16 + (size_t)t * 128, 256);
        }
    }

    // ---- temporal attention ----
    {
        dim3 g(GX2, 3);
        gemm_mfma<<<g, 256, 0, stream>>>(st16, Wqkv16, bqkv, nullptr, qkv16,
                                         2 * N, 128, 384, nullptr, nullptr,
                                         nullptr, nullptr, 0);
    }
    temporal_attn<<<N, 128, 0, stream>>>(qkv16, om16);
    {
        dim3 g(GX, 1);
        gemm_mfma<<<g, 256, 0, stream>>>(om16, Wo16, bo, out, nullptr,
                                         N, 128, 128, nullptr, nullptr,
                                         nullptr, nullptr, 0);
    }
}

// Round 26
// 474.595 us; speedup vs baseline: 1.1638x; 1.0674x over previous
//
#include <hip/hip_runtime.h>
#include <math.h>

#define N_NODES 20000
#define N_EDGES 256000
#define ETOT (N_EDGES + N_NODES)
#define NPAD 20096    // 314*64
#define NPAD2 40064   // 626*64
#define NBLK_SCAN ((N_NODES + 255) / 256)   // 79

typedef __attribute__((ext_vector_type(8))) short bf16x8;
typedef __attribute__((ext_vector_type(4))) float f32x4;

__device__ __forceinline__ unsigned short f2bf(float f) {
    unsigned int u = __builtin_bit_cast(unsigned int, f);
    u = (u + 0x7fff + ((u >> 16) & 1)) >> 16;
    return (unsigned short)u;
}

__device__ __forceinline__ float bf2f(unsigned short u) {
    return __builtin_bit_cast(float, (unsigned int)u << 16);
}

__device__ __forceinline__ void gload_lds16(const void* g, void* l) {
    __builtin_amdgcn_global_load_lds(
        (const __attribute__((address_space(1))) void*)g,
        (__attribute__((address_space(3))) void*)l, 16, 0, 0);
}

// unpack uint4 (8 bf16) and fma into acc[8]
__device__ __forceinline__ void fma8(float* acc, uint4 v, float w) {
    acc[0] = fmaf(w, __builtin_bit_cast(float, v.x << 16), acc[0]);
    acc[1] = fmaf(w, __builtin_bit_cast(float, v.x & 0xffff0000u), acc[1]);
    acc[2] = fmaf(w, __builtin_bit_cast(float, v.y << 16), acc[2]);
    acc[3] = fmaf(w, __builtin_bit_cast(float, v.y & 0xffff0000u), acc[3]);
    acc[4] = fmaf(w, __builtin_bit_cast(float, v.z << 16), acc[4]);
    acc[5] = fmaf(w, __builtin_bit_cast(float, v.z & 0xffff0000u), acc[5]);
    acc[6] = fmaf(w, __builtin_bit_cast(float, v.w << 16), acc[6]);
    acc[7] = fmaf(w, __builtin_bit_cast(float, v.w & 0xffff0000u), acc[7]);
}

// ---------------------------------------------------------------------------
// Edge preprocessing: counting sort by dst, deterministic order within segment
// ---------------------------------------------------------------------------

__global__ void hist_kernel(const int* __restrict__ ei, int* __restrict__ cnt) {
    for (int e = blockIdx.x * blockDim.x + threadIdx.x; e < ETOT;
         e += gridDim.x * blockDim.x) {
        int d = (e < N_EDGES) ? ei[N_EDGES + e] : (e - N_EDGES);
        atomicAdd(&cnt[d], 1);
    }
}

__global__ __launch_bounds__(256) void scanA(const int* __restrict__ cnt,
                                             int* __restrict__ incl,
                                             int* __restrict__ bsum) {
    __shared__ int sh[256];
    int t = threadIdx.x;
    int i = blockIdx.x * 256 + t;
    int v = (i < N_NODES) ? cnt[i] : 0;
    sh[t] = v;
    __syncthreads();
#pragma unroll
    for (int off = 1; off < 256; off <<= 1) {
        int u = (t >= off) ? sh[t - off] : 0;
        __syncthreads();
        sh[t] += u;
        __syncthreads();
    }
    if (i < N_NODES) incl[i] = sh[t];
    if (t == 255) bsum[blockIdx.x] = sh[255];
}

__global__ __launch_bounds__(128) void scanB(int* __restrict__ bsum,
                                             int* __restrict__ row_start) {
    __shared__ int sh[128];
    int t = threadIdx.x;
    int v = (t < NBLK_SCAN) ? bsum[t] : 0;
    sh[t] = v;
    __syncthreads();
#pragma unroll
    for (int off = 1; off < 128; off <<= 1) {
        int u = (t >= off) ? sh[t - off] : 0;
        __syncthreads();
        sh[t] += u;
        __syncthreads();
    }
    if (t < NBLK_SCAN) bsum[t] = sh[t] - v;  // exclusive
    if (t == 0) row_start[0] = 0;
}

__global__ __launch_bounds__(256) void scanC(int* __restrict__ cursor,
                                             int* __restrict__ row_start,
                                             const int* __restrict__ bsum) {
    int i = blockIdx.x * 256 + threadIdx.x;
    if (i < N_NODES) {
        int incl = row_start[i + 1] + bsum[blockIdx.x];
        row_start[i + 1] = incl;
        cursor[i] = incl - cursor[i];
    }
}

__global__ void scatter_kernel(const int* __restrict__ ei, int* __restrict__ cursor,
                               int* __restrict__ sorted_id) {
    for (int e = blockIdx.x * blockDim.x + threadIdx.x; e < ETOT;
         e += gridDim.x * blockDim.x) {
        int d = (e < N_EDGES) ? ei[N_EDGES + e] : (e - N_EDGES);
        int pos = atomicAdd(&cursor[d], 1);
        sorted_id[pos] = e;
    }
}

// Deterministic order via wave-parallel rank sort: one wave per node.
__global__ __launch_bounds__(256) void segsort_kernel(
    const int* __restrict__ ei, const int* __restrict__ row_start,
    int* __restrict__ sorted_id, int* __restrict__ sorted_src) {
    int wv = threadIdx.x >> 6, lane = threadIdx.x & 63;
    int n = blockIdx.x * 4 + wv;
    if (n >= N_NODES) return;
    int base = row_start[n];
    int deg = row_start[n + 1] - base;
    if (deg <= 64) {
        int id = (lane < deg) ? sorted_id[base + lane] : 0x7fffffff;
        int rank = 0;
        for (int j = 0; j < deg; j++) {
            int idj = __shfl(id, j);
            rank += (idj < id);
        }
        if (lane < deg) {
            int src = (id < N_EDGES) ? ei[id] : (id - N_EDGES);
            sorted_src[base + rank] = src;
        }
    } else if (lane == 0) {
        for (int i = base + 1; i < base + deg; i++) {
            int v = sorted_id[i];
            int j = i - 1;
            while (j >= base && sorted_id[j] > v) {
                sorted_id[j + 1] = sorted_id[j];
                j--;
            }
            sorted_id[j + 1] = v;
        }
        for (int i = base; i < base + deg; i++) {
            int id = sorted_id[i];
            sorted_src[i] = (id < N_EDGES) ? ei[id] : (id - N_EDGES);
        }
    }
}

// ---------------------------------------------------------------------------
// One-launch setup: cursor zeroing + pad-row zeroing + bf16 conversions
// ---------------------------------------------------------------------------
struct SetupArgs {
    const float* s[7];
    unsigned short* d[7];
    int cum[8];
    int* cursor;
    unsigned short* x16;
    unsigned short* h16n;
    unsigned short* h16wA;
    unsigned short* h16wB;
    unsigned short* st16;
    unsigned short* om16;
};

__global__ __launch_bounds__(256) void setup_all(SetupArgs a) {
    int i = blockIdx.x * 256 + threadIdx.x;
    const int PR = NPAD - N_NODES;  // 96 pad rows
    if (i < N_NODES) a.cursor[i] = 0;
    if (i < PR * 128) {
        a.x16[(size_t)N_NODES * 128 + i] = 0;
        a.h16n[(size_t)N_NODES * 128 + i] = 0;
        a.om16[(size_t)N_NODES * 128 + i] = 0;
    }
    if (i < PR * 512) {
        a.h16wA[(size_t)N_NODES * 512 + i] = 0;
        a.h16wB[(size_t)N_NODES * 512 + i] = 0;
    }
    if (i < (NPAD2 - 2 * N_NODES) * 128) a.st16[(size_t)(2 * N_NODES) * 128 + i] = 0;
    if (i < a.cum[7]) {
        int r = 0;
        while (i >= a.cum[r + 1]) r++;
        int off = i - a.cum[r];
        a.d[r][off] = f2bf(a.s[r][off]);
    }
}

// ---------------------------------------------------------------------------
// bf16 MFMA GEMM, 64x128 tile (BK=64, 4 waves each 32x64).
// Optional fused GAT attention-coefficient epilogue (head = blockIdx.y).
// ---------------------------------------------------------------------------
__global__ __launch_bounds__(256) void gemm_mfma(
    const unsigned short* __restrict__ A, const unsigned short* __restrict__ B,
    const float* __restrict__ bias, float* __restrict__ Cf,
    unsigned short* __restrict__ C16, int R, int K, int ldc,
    const float* __restrict__ a_s, const float* __restrict__ a_d,
    float* __restrict__ al_s, float* __restrict__ al_d, int H) {
    __shared__ unsigned short Al[64 * 64];
    __shared__ unsigned short Bl[128 * 64];
    __shared__ float red_s[4][32], red_d[4][32];
    int tid = threadIdx.x;
    int lane = tid & 63, wv = tid >> 6;
    int wr = (wv >> 1) * 32, wc = (wv & 1) * 64;
    size_t br = (size_t)blockIdx.x * 64;
    size_t bc = (size_t)blockIdx.y * 128;
    f32x4 acc[2][4] = {};
    for (int k0 = 0; k0 < K; k0 += 64) {
#pragma unroll
        for (int i = 0; i < 2; i++) {
            int idx = i * 256 + tid;
            int row = idx >> 3;
            int kb = (idx & 7) << 4;
            gload_lds16((const char*)(A + (br + row) * K + k0) + kb,
                        (char*)Al + idx * 16);
        }
#pragma unroll
        for (int i = 0; i < 4; i++) {
            int idx = i * 256 + tid;
            int row = idx >> 3;
            int kb = (idx & 7) << 4;
            gload_lds16((const char*)(B + (bc + row) * K + k0) + kb,
                        (char*)Bl + idx * 16);
        }
        __syncthreads();
#pragma unroll
        for (int kk = 0; kk < 2; kk++) {
            bf16x8 af[2], bfr[4];
#pragma unroll
            for (int m = 0; m < 2; m++)
                af[m] = *(const bf16x8*)&Al[(wr + m * 16 + (lane & 15)) * 64 +
                                            kk * 32 + (lane >> 4) * 8];
#pragma unroll
            for (int n = 0; n < 4; n++)
                bfr[n] = *(const bf16x8*)&Bl[(wc + n * 16 + (lane & 15)) * 64 +
                                             kk * 32 + (lane >> 4) * 8];
#pragma unroll
            for (int m = 0; m < 2; m++)
#pragma unroll
                for (int n = 0; n < 4; n++)
                    acc[m][n] = __builtin_amdgcn_mfma_f32_16x16x32_bf16(
                        af[m], bfr[n], acc[m][n], 0, 0, 0);
        }
        __syncthreads();
    }

    if (al_s) {
        float asr[4], adr[4];
#pragma unroll
        for (int n = 0; n < 4; n++) {
            int c = (int)bc + wc + n * 16 + (lane & 15);
            asr[n] = a_s[c];
            adr[n] = a_d[c];
        }
        float ps[2][4], pd[2][4];
#pragma unroll
        for (int m = 0; m < 2; m++)
#pragma unroll
            for (int j = 0; j < 4; j++) {
                float s = 0.f, d = 0.f;
#pragma unroll
                for (int n = 0; n < 4; n++) {
                    float v = acc[m][n][j];
                    s = fmaf(v, asr[n], s);
                    d = fmaf(v, adr[n], d);
                }
#pragma unroll
                for (int off = 8; off; off >>= 1) {
                    s += __shfl_xor(s, off);
                    d += __shfl_xor(d, off);
                }
                ps[m][j] = s;
                pd[m][j] = d;
            }
        if ((lane & 15) == 0) {
#pragma unroll
            for (int m = 0; m < 2; m++)
#pragma unroll
                for (int j = 0; j < 4; j++) {
                    int lr = m * 16 + (lane >> 4) * 4 + j;  // 0..31
                    red_s[wv][lr] = ps[m][j];
                    red_d[wv][lr] = pd[m][j];
                }
        }
        __syncthreads();
        if (tid < 64) {
            int half = tid >> 5, lr = tid & 31;
            float s = red_s[half * 2][lr] + red_s[half * 2 + 1][lr];
            float d = red_d[half * 2][lr] + red_d[half * 2 + 1][lr];
            size_t r = br + half * 32 + lr;
            if (r < (size_t)R) {
                al_s[r * H + blockIdx.y] = s;
                al_d[r * H + blockIdx.y] = d;
            }
        }
    }

#pragma unroll
    for (int m = 0; m < 2; m++) {
        int r0 = wr + m * 16 + (lane >> 4) * 4;
#pragma unroll
        for (int n = 0; n < 4; n++) {
            int c = (int)bc + wc + n * 16 + (lane & 15);
            float bv = bias ? bias[c] : 0.f;
#pragma unroll
            for (int j = 0; j < 4; j++) {
                size_t r = br + r0 + j;
                if (r < (size_t)R) {
                    float v = acc[m][n][j] + bv;
                    if (Cf) Cf[r * ldc + c] = v;
                    if (C16) C16[r * ldc + c] = f2bf(v);
                }
            }
        }
    }
}

// ---------------------------------------------------------------------------
// Wave-per-node GAT aggregation for C=512 (4 heads): one wave owns one node.
// ---------------------------------------------------------------------------
template <int RES>
__global__ __launch_bounds__(256) void gat_agg512(
    const unsigned short* __restrict__ xp16, const float* __restrict__ al_s,
    const float* __restrict__ al_d, const int* __restrict__ row_start,
    const int* __restrict__ srcs, const float* __restrict__ bias,
    const float* __restrict__ gamma, const float* __restrict__ beta,
    const unsigned short* __restrict__ h_res16, unsigned short* __restrict__ out16) {
    const int C = 512;
    int tid = threadIdx.x;
    int lane = tid & 63, wv = tid >> 6;
    int n = blockIdx.x * 4 + wv;
    __shared__ int offw[4][64];
    __shared__ float logw[4][256];
    if (n >= N_NODES) return;
    int base = row_start[n];
    int deg = row_start[n + 1] - base;
    int head = lane >> 4;

    float acc[8] = {};
    float scale_end;

    if (deg <= 64) {
        int e_ = lane >> 2, h_ = lane & 3;
        float m = -3.4e38f;
        for (int e0 = 0; e0 < deg; e0 += 16) {
            int e = e0 + e_;
            float v = -3.4e38f;
            if (e < deg) {
                int src = srcs[base + e];
                if (h_ == 0) offw[wv][e] = src * (C * 2);
                float t = al_s[src * 4 + h_] + al_d[n * 4 + h_];
                v = t > 0.f ? t : 0.2f * t;
                logw[wv][e * 4 + h_] = v;
            }
            m = fmaxf(m, v);
        }
#pragma unroll
        for (int off = 4; off <= 32; off <<= 1) m = fmaxf(m, __shfl_xor(m, off));
        float s = 0.f;
        for (int e0 = 0; e0 < deg; e0 += 16) {
            int e = e0 + e_;
            if (e < deg) {
                float p = __expf(logw[wv][e * 4 + h_] - m);
                logw[wv][e * 4 + h_] = p;
                s += p;
            }
        }
#pragma unroll
        for (int off = 4; off <= 32; off <<= 1) s += __shfl_xor(s, off);
        float inv = 1.0f / (s + 1e-16f);
        scale_end = __shfl(inv, head);
        const char* xb = (const char*)xp16 + lane * 16;
#pragma unroll 4
        for (int j = 0; j < deg; j++) {
            float w = logw[wv][j * 4 + head];
            uint4 vv = *(const uint4*)(xb + offw[wv][j]);
            fma8(acc, vv, w);
        }
    } else {
        int e_ = lane >> 2, h_ = lane & 3;
        float m = -3.4e38f;
        for (int e0 = 0; e0 < deg; e0 += 16) {
            int e = e0 + e_;
            if (e < deg) {
                int src = srcs[base + e];
                float t = al_s[src * 4 + h_] + al_d[n * 4 + h_];
                t = t > 0.f ? t : 0.2f * t;
                m = fmaxf(m, t);
            }
        }
#pragma unroll
        for (int off = 4; off <= 32; off <<= 1) m = fmaxf(m, __shfl_xor(m, off));
        float s = 0.f;
        for (int e0 = 0; e0 < deg; e0 += 16) {
            int e = e0 + e_;
            if (e < deg) {
                int src = srcs[base + e];
                float t = al_s[src * 4 + h_] + al_d[n * 4 + h_];
                t = t > 0.f ? t : 0.2f * t;
                s += __expf(t - m);
            }
        }
#pragma unroll
        for (int off = 4; off <= 32; off <<= 1) s += __shfl_xor(s, off);
        float mg = __shfl(m, head);
        float sg = __shfl(s, head);
        float invg = 1.0f / (sg + 1e-16f);
        float aldh = al_d[n * 4 + head];
        const char* xb = (const char*)xp16 + lane * 16;
        for (int j = 0; j < deg; j++) {
            int src = srcs[base + j];
            float t = al_s[src * 4 + head] + aldh;
            t = t > 0.f ? t : 0.2f * t;
            float w = __expf(t - mg) * invg;
            uint4 vv = *(const uint4*)(xb + (size_t)src * (C * 2));
            fma8(acc, vv, w);
        }
        scale_end = 1.0f;
    }

    // ---- epilogue: scale, +bias, ELU, LayerNorm (64-lane), residual ----
    int ch0 = 8 * lane;
    float vals[8];
    {
        float4 b0 = *(const float4*)&bias[ch0];
        float4 b1 = *(const float4*)&bias[ch0 + 4];
        vals[0] = acc[0] * scale_end + b0.x;
        vals[1] = acc[1] * scale_end + b0.y;
        vals[2] = acc[2] * scale_end + b0.z;
        vals[3] = acc[3] * scale_end + b0.w;
        vals[4] = acc[4] * scale_end + b1.x;
        vals[5] = acc[5] * scale_end + b1.y;
        vals[6] = acc[6] * scale_end + b1.z;
        vals[7] = acc[7] * scale_end + b1.w;
    }
    float s2 = 0.f, q = 0.f;
#pragma unroll
    for (int k = 0; k < 8; k++) {
        vals[k] = vals[k] > 0.f ? vals[k] : (__expf(vals[k]) - 1.0f);
        s2 += vals[k];
        q += vals[k] * vals[k];
    }
#pragma unroll
    for (int off = 1; off <= 32; off <<= 1) {
        s2 += __shfl_xor(s2, off);
        q += __shfl_xor(q, off);
    }
    float mu = s2 / C;
    float var = q / C - mu * mu;
    float rstd = 1.0f / sqrtf(var + 1e-5f);
    {
        float4 g0 = *(const float4*)&gamma[ch0];
        float4 g1 = *(const float4*)&gamma[ch0 + 4];
        float4 be0v = *(const float4*)&beta[ch0];
        float4 be1v = *(const float4*)&beta[ch0 + 4];
        float gg[8] = {g0.x, g0.y, g0.z, g0.w, g1.x, g1.y, g1.z, g1.w};
        float bb[8] = {be0v.x, be0v.y, be0v.z, be0v.w,
                       be1v.x, be1v.y, be1v.z, be1v.w};
#pragma unroll
        for (int k = 0; k < 8; k++) vals[k] = (vals[k] - mu) * rstd * gg[k] + bb[k];
    }
    if (RES == 1) {
        ushort4 r0 = *(const ushort4*)&h_res16[(size_t)n * C + ch0];
        ushort4 r1 = *(const ushort4*)&h_res16[(size_t)n * C + ch0 + 4];
        vals[0] += bf2f(r0.x); vals[1] += bf2f(r0.y);
        vals[2] += bf2f(r0.z); vals[3] += bf2f(r0.w);
        vals[4] += bf2f(r1.x); vals[5] += bf2f(r1.y);
        vals[6] += bf2f(r1.z); vals[7] += bf2f(r1.w);
    }
    uint4 pk;
    pk.x = (unsigned)f2bf(vals[0]) | ((unsigned)f2bf(vals[1]) << 16);
    pk.y = (unsigned)f2bf(vals[2]) | ((unsigned)f2bf(vals[3]) << 16);
    pk.z = (unsigned)f2bf(vals[4]) | ((unsigned)f2bf(vals[5]) << 16);
    pk.w = (unsigned)f2bf(vals[6]) | ((unsigned)f2bf(vals[7]) << 16);
    *(uint4*)&out16[(size_t)n * C + ch0] = pk;
}

// ---------------------------------------------------------------------------
// C=128, 1-head aggregation (one wave per node, 16 lanes/row, 4 edge groups)
// ---------------------------------------------------------------------------
__global__ __launch_bounds__(64) void gat_agg128(
    const unsigned short* __restrict__ xp16, const float* __restrict__ al_s,
    const float* __restrict__ al_d, const int* __restrict__ row_start,
    const int* __restrict__ srcs, const float* __restrict__ bias,
    const float* __restrict__ gamma, const float* __restrict__ beta,
    const unsigned short* __restrict__ h_res16, unsigned short* __restrict__ out16,
    unsigned short* __restrict__ out2_16, int out2_stride) {
    const int C = 128;
    int n = blockIdx.x;
    int lane = threadIdx.x & 63;
    __shared__ int off_sh[64];
    __shared__ float w_sh[64];
    __shared__ float m_sh, s_sh;
    int base = row_start[n];
    int deg = row_start[n + 1] - base;

    float acc[8] = {};

    if (deg <= 64) {
        float v = -3.4e38f;
        if (lane < deg) {
            int src = srcs[base + lane];
            off_sh[lane] = src * (C * 2);
            float t = al_s[src] + al_d[n];
            v = t > 0.f ? t : 0.2f * t;
        }
        float m = v;
#pragma unroll
        for (int off = 32; off; off >>= 1) m = fmaxf(m, __shfl_xor(m, off));
        float p = (lane < deg) ? __expf(v - m) : 0.f;
        float s = p;
#pragma unroll
        for (int off = 32; off; off >>= 1) s += __shfl_xor(s, off);
        s += 1e-16f;
        if (lane < deg) w_sh[lane] = p / s;
        __syncthreads();
        int li = lane & 15, rg = lane >> 4;
        const char* xb = (const char*)xp16 + li * 16;
        for (int j = rg; j < deg; j += 4) {
            uint4 vv = *(const uint4*)(xb + off_sh[j]);
            fma8(acc, vv, w_sh[j]);
        }
    } else {
        float ald = al_d[n];
        float m = -3.4e38f;
        for (int e = lane; e < deg; e += 64) {
            float v = al_s[srcs[base + e]] + ald;
            v = v > 0.f ? v : 0.2f * v;
            m = fmaxf(m, v);
        }
#pragma unroll
        for (int off = 32; off; off >>= 1) m = fmaxf(m, __shfl_xor(m, off));
        float s = 0.f;
        for (int e = lane; e < deg; e += 64) {
            float v = al_s[srcs[base + e]] + ald;
            v = v > 0.f ? v : 0.2f * v;
            s += __expf(v - m);
        }
#pragma unroll
        for (int off = 32; off; off >>= 1) s += __shfl_xor(s, off);
        if (lane == 0) { m_sh = m; s_sh = s + 1e-16f; }
        __syncthreads();
        float mh = m_sh, ssh = s_sh;
        int li = lane & 15, rg = lane >> 4;
        const char* xb = (const char*)xp16 + li * 16;
        for (int j = rg; j < deg; j += 4) {
            int src = srcs[base + j];
            float t = al_s[src] + ald;
            t = t > 0.f ? t : 0.2f * t;
            float w = __expf(t - mh) / ssh;
            uint4 vv = *(const uint4*)(xb + (size_t)src * (C * 2));
            fma8(acc, vv, w);
        }
    }

    // combine 4 edge-groups via shfl; 8 ch/lane epilogue
#pragma unroll
    for (int k = 0; k < 8; k++) {
        acc[k] += __shfl_xor(acc[k], 16);
        acc[k] += __shfl_xor(acc[k], 32);
    }
    int li = lane & 15;
    int ch0 = 8 * li;
    float vals[8];
    float4 b0 = *(const float4*)&bias[ch0];
    float4 b1 = *(const float4*)&bias[ch0 + 4];
    vals[0] = acc[0] + b0.x; vals[1] = acc[1] + b0.y;
    vals[2] = acc[2] + b0.z; vals[3] = acc[3] + b0.w;
    vals[4] = acc[4] + b1.x; vals[5] = acc[5] + b1.y;
    vals[6] = acc[6] + b1.z; vals[7] = acc[7] + b1.w;
    float s = 0.f, q = 0.f;
#pragma unroll
    for (int k = 0; k < 8; k++) {
        vals[k] = vals[k] > 0.f ? vals[k] : (__expf(vals[k]) - 1.0f);
        s += vals[k];
        q += vals[k] * vals[k];
    }
#pragma unroll
    for (int off = 8; off; off >>= 1) {
        s += __shfl_xor(s, off);
        q += __shfl_xor(q, off);
    }
    float mu = s / C;
    float var = q / C - mu * mu;
    float rstd = 1.0f / sqrtf(var + 1e-5f);
    float4 g0 = *(const float4*)&gamma[ch0];
    float4 g1 = *(const float4*)&gamma[ch0 + 4];
    float4 be0v = *(const float4*)&beta[ch0];
    float4 be1v = *(const float4*)&beta[ch0 + 4];
    float gg[8] = {g0.x, g0.y, g0.z, g0.w, g1.x, g1.y, g1.z, g1.w};
    float bb[8] = {be0v.x, be0v.y, be0v.z, be0v.w, be1v.x, be1v.y, be1v.z, be1v.w};
#pragma unroll
    for (int k = 0; k < 8; k++) vals[k] = (vals[k] - mu) * rstd * gg[k] + bb[k];
    {
        const unsigned short* r = &h_res16[(size_t)n * 512 + 4 * ch0];
#pragma unroll
        for (int k = 0; k < 8; k++) {
            ushort4 rv = *(const ushort4*)&r[4 * k];
            vals[k] += 0.25f * (bf2f(rv.x) + bf2f(rv.y) + bf2f(rv.z) + bf2f(rv.w));
        }
    }
    if (lane < 16) {
        uint4 pk;
        pk.x = (unsigned)f2bf(vals[0]) | ((unsigned)f2bf(vals[1]) << 16);
        pk.y = (unsigned)f2bf(vals[2]) | ((unsigned)f2bf(vals[3]) << 16);
        pk.z = (unsigned)f2bf(vals[4]) | ((unsigned)f2bf(vals[5]) << 16);
        pk.w = (unsigned)f2bf(vals[6]) | ((unsigned)f2bf(vals[7]) << 16);
        if (out16) *(uint4*)&out16[(size_t)n * C + ch0] = pk;
        if (out2_16) *(uint4*)&out2_16[(size_t)n * out2_stride + ch0] = pk;
    }
}

// ---------------------------------------------------------------------------
// Temporal self-attention over T=2 states. qkv16:[2N,384] bf16 -> om16 bf16
// ---------------------------------------------------------------------------
__global__ __launch_bounds__(128) void temporal_attn(
    const unsigned short* __restrict__ qkv16, unsigned short* __restrict__ om16) {
    __shared__ float sh[768];
    int n = blockIdx.x;
    int c = threadIdx.x;
    for (int i = c; i < 768; i += 128) {
        int t = i / 384;
        sh[i] = bf2f(qkv16[(size_t)(n * 2 + t) * 384 + (i - t * 384)]);
    }
    __syncthreads();
    int head = c >> 5;
    int hb = head * 32;
    const float scale = 0.17677669529663687f;
    float o[2];
#pragma unroll
    for (int qt = 0; qt < 2; qt++) {
        float s0 = 0.f, s1 = 0.f;
#pragma unroll
        for (int d = 0; d < 32; d++) {
            float qv = sh[qt * 384 + hb + d];
            s0 = fmaf(qv, sh[0 * 384 + 128 + hb + d], s0);
            s1 = fmaf(qv, sh[1 * 384 + 128 + hb + d], s1);
        }
        s0 *= scale; s1 *= scale;
        float m = fmaxf(s0, s1);
        float p0 = __expf(s0 - m), p1 = __expf(s1 - m);
        float inv = 1.0f / (p0 + p1);
        o[qt] = p0 * inv * sh[0 * 384 + 256 + c] + p1 * inv * sh[1 * 384 + 256 + c];
    }
    om16[(size_t)n * 128 + c] = f2bf(0.5f * (o[0] + o[1]));
}

// ---------------------------------------------------------------------------

extern "C" void kernel_launch(void* const* d_in, const int* in_sizes, int n_in,
                              void* d_out, int out_size, void* d_ws, size_t ws_size,
                              hipStream_t stream) {
    const float* x   = (const float*)d_in[0];
    const int*   ei  = (const int*)d_in[1];
    const float* Wp  = (const float*)d_in[2];
    const float* bp  = (const float*)d_in[3];
    const float* W0  = (const float*)d_in[4];
    const float* as0 = (const float*)d_in[5];
    const float* ad0 = (const float*)d_in[6];
    const float* b0  = (const float*)d_in[7];
    const float* W1  = (const float*)d_in[8];
    const float* as1 = (const float*)d_in[9];
    const float* ad1 = (const float*)d_in[10];
    const float* b1  = (const float*)d_in[11];
    const float* W2  = (const float*)d_in[12];
    const float* as2 = (const float*)d_in[13];
    const float* ad2 = (const float*)d_in[14];
    const float* b2  = (const float*)d_in[15];
    const float* g0  = (const float*)d_in[16];
    const float* be0 = (const float*)d_in[17];
    const float* g1  = (const float*)d_in[18];
    const float* be1 = (const float*)d_in[19];
    const float* g2  = (const float*)d_in[20];
    const float* be2 = (const float*)d_in[21];
    const float* Wqkv = (const float*)d_in[22];
    const float* bqkv = (const float*)d_in[23];
    const float* Wo  = (const float*)d_in[24];
    const float* bo  = (const float*)d_in[25];
    float* out = (float*)d_out;

    const int N = N_NODES;
    float* f = (float*)d_ws;
    // fp32 buffers (attention coefficients only)
    float* als = f;                     // [N,4]
    float* ald = als + (size_t)N * 4;   // [N,4]
    // int buffers
    int* row_start  = (int*)(ald + (size_t)N * 4);
    int* cursor     = row_start + (N + 1);
    int* sorted_id  = cursor + N;
    int* sorted_src = sorted_id + ETOT;
    int* bsum       = sorted_src + ETOT;          // NBLK_SCAN
    // bf16 buffers (aligned to 64B for uint4 / global_load_lds dwordx4)
    uintptr_t pa = (uintptr_t)(bsum + NBLK_SCAN + 1);
    pa = (pa + 63) & ~(uintptr_t)63;
    unsigned short* x16   = (unsigned short*)pa;
    unsigned short* h16n  = x16 + (size_t)NPAD * 128;         // [NPAD,128]
    unsigned short* h16wA = h16n + (size_t)NPAD * 128;        // [NPAD,512]
    unsigned short* h16wB = h16wA + (size_t)NPAD * 512;       // [NPAD,512]
    unsigned short* xp16  = h16wB + (size_t)NPAD * 512;       // [NPAD,512]
    unsigned short* st16  = xp16 + (size_t)NPAD * 512;        // [NPAD2,128]
    unsigned short* qkv16 = st16 + (size_t)NPAD2 * 128;       // [NPAD2,384]
    unsigned short* om16  = qkv16 + (size_t)NPAD2 * 384;      // [NPAD,128]
    unsigned short* w16   = om16 + (size_t)NPAD * 128;
    unsigned short* Wp16   = w16;
    unsigned short* W016   = Wp16 + 128 * 128;
    unsigned short* W116   = W016 + 512 * 128;
    unsigned short* W216   = W116 + 512 * 512;
    unsigned short* Wqkv16 = W216 + 128 * 512;
    unsigned short* Wo16   = Wqkv16 + 384 * 128;

    // ---- one-launch setup: cursor zero + pad zero + bf16 conversions ----
    {
        SetupArgs a;
        const float* srcs7[7] = {Wp, W0, W1, W2, Wqkv, Wo, x};
        unsigned short* dsts7[7] = {Wp16, W016, W116, W216, Wqkv16, Wo16, x16};
        int sizes7[7] = {128 * 128, 512 * 128, 512 * 512, 128 * 512,
                         384 * 128, 128 * 128, N_NODES * 128};
        int c = 0;
        a.cum[0] = 0;
        for (int i = 0; i < 7; i++) {
            a.s[i] = srcs7[i];
            a.d[i] = dsts7[i];
            c += sizes7[i];
            a.cum[i + 1] = c;
        }
        a.cursor = cursor;
        a.x16 = x16; a.h16n = h16n; a.h16wA = h16wA; a.h16wB = h16wB;
        a.st16 = st16; a.om16 = om16;
        setup_all<<<(c + 255) / 256, 256, 0, stream>>>(a);
    }

    // ---- edge preprocessing (deterministic counting sort by dst) ----
    hist_kernel<<<1024, 256, 0, stream>>>(ei, cursor);
    scanA<<<NBLK_SCAN, 256, 0, stream>>>(cursor, row_start + 1, bsum);
    scanB<<<1, 128, 0, stream>>>(bsum, row_start);
    scanC<<<NBLK_SCAN, 256, 0, stream>>>(cursor, row_start, bsum);
    scatter_kernel<<<1024, 256, 0, stream>>>(ei, cursor, sorted_id);
    segsort_kernel<<<(N + 3) / 4, 256, 0, stream>>>(ei, row_start, sorted_id,
                                                    sorted_src);

    const int GX = NPAD / 64;   // 314
    const int GX2 = NPAD2 / 64; // 626
    const int GA = (N + 3) / 4; // 5000 blocks for wave-per-node agg512
    // ---- input projection -> h16n ----
    {
        dim3 g(GX, 1);
        gemm_mfma<<<g, 256, 0, stream>>>(x16, Wp16, bp, nullptr, h16n, N, 128, 128,
                                         nullptr, nullptr, nullptr, nullptr, 0);
    }

    for (int t = 0; t < 2; t++) {
        // layer 0: 128 -> 512 (4 heads), no residual
        {
            dim3 g(GX, 4);
            gemm_mfma<<<g, 256, 0, stream>>>(h16n, W016, nullptr, nullptr, xp16,
                                             N, 128, 512, as0, ad0, als, ald, 4);
            gat_agg512<0><<<GA, 256, 0, stream>>>(
                xp16, als, ald, row_start, sorted_src, b0, g0, be0, nullptr, h16wA);
        }
        // layer 1: 512 -> 512 (4 heads), residual = h16wA
        {
            dim3 g(GX, 4);
            gemm_mfma<<<g, 256, 0, stream>>>(h16wA, W116, nullptr, nullptr, xp16,
                                             N, 512, 512, as1, ad1, als, ald, 4);
            gat_agg512<1><<<GA, 256, 0, stream>>>(
                xp16, als, ald, row_start, sorted_src, b1, g1, be1, h16wA, h16wB);
        }
        // layer 2: 512 -> 128 (1 head), pooled residual = h16wB
        {
            dim3 g(GX, 1);
            gemm_mfma<<<g, 256, 0, stream>>>(h16wB, W216, nullptr, nullptr, xp16,
                                             N, 512, 128, as2, ad2, als, ald, 1);
            gat_agg128<<<N, 64, 0, stream>>>(
                xp16, als, ald, row_start, sorted_src, b2, g2, be2, h16wB,
                (t == 0) ? h16n : nullptr, st16 + (size_t)t * 128, 256);
        }
    }

    // ---- temporal attention ----
    {
        dim3 g(GX2, 3);
        gemm_mfma<<<g, 256, 0, stream>>>(st16, Wqkv16, bqkv, nullptr, qkv16,
                                         2 * N, 128, 384, nullptr, nullptr,
                                         nullptr, nullptr, 0);
    }
    temporal_attn<<<N, 128, 0, stream>>>(qkv16, om16);
    {
        dim3 g(GX, 1);
        gemm_mfma<<<g, 256, 0, stream>>>(om16, Wo16, bo, out, nullptr,
                                         N, 128, 128, nullptr, nullptr,
                                         nullptr, nullptr, 0);
    }
}